// Round 2
// baseline (3396.632 us; speedup 1.0000x reference)
//
#include <hip/hip_runtime.h>

#define N_NODES  20000
#define N_EDGES  320000
#define R_REL    40
#define N_BASES  34
#define DIM      128
#define EB       64                       // edges per block (edge GEMM tile M)
#define P_MAX    (N_EDGES + R_REL * EB)   // 322560 max padded sorted edges

// ---------------- utility: zero int buffer ----------------
__global__ void zero_kernel(int* __restrict__ p, int n) {
    int i = blockIdx.x * blockDim.x + threadIdx.x;
    if (i < n) p[i] = 0;
}

// ---------------- fill sorted-edge arrays with sentinel ----------------
__global__ void fill_kernel(int* __restrict__ srcs, int* __restrict__ dsts) {
    int i = blockIdx.x * blockDim.x + threadIdx.x;
    if (i < P_MAX) { srcs[i] = -1; dsts[i] = 0; }
}

// ---------------- counts c[dst*R+et] and relation histogram ----------------
__global__ void count_kernel(const int* __restrict__ ei, const int* __restrict__ et,
                             int* __restrict__ c, int* __restrict__ h) {
    int e = blockIdx.x * blockDim.x + threadIdx.x;
    if (e >= N_EDGES) return;
    int dst = ei[N_EDGES + e];
    int r   = et[e];
    atomicAdd(&c[dst * R_REL + r], 1);
    atomicAdd(&h[r], 1);
}

// ---------------- finv = 1/max(c,1) ----------------
__global__ void inv_kernel(const int* __restrict__ c, float* __restrict__ finv) {
    int i = blockIdx.x * blockDim.x + threadIdx.x;
    if (i < N_NODES * R_REL) {
        int v = c[i];
        finv[i] = 1.0f / (float)(v < 1 ? 1 : v);
    }
}

// ---------------- padded exclusive scan of histogram (tiny, 1 thread) ----------------
__global__ void scan_kernel(const int* __restrict__ h, int* __restrict__ off) {
    if (blockIdx.x == 0 && threadIdx.x == 0) {
        int acc = 0;
        off[0] = 0;
        for (int r = 0; r < R_REL; ++r) {
            int p = ((h[r] + EB - 1) / EB) * EB;
            acc += p;
            off[r + 1] = acc;
        }
    }
}

// ---------------- counting-sort placement of edges by relation ----------------
__global__ void place_kernel(const int* __restrict__ ei, const int* __restrict__ et,
                             const int* __restrict__ off, int* __restrict__ cur,
                             int* __restrict__ srcs, int* __restrict__ dsts) {
    int e = blockIdx.x * blockDim.x + threadIdx.x;
    if (e >= N_EDGES) return;
    int r = et[e];
    int p = off[r] + atomicAdd(&cur[r], 1);
    srcs[p] = ei[e];
    dsts[p] = ei[N_EDGES + e];
}

// ---------------- gather: x0[n,:] = node_emb[node_index[n],:] ----------------
__global__ void gather_kernel(const float* __restrict__ emb,
                              const int* __restrict__ idx,
                              float* __restrict__ x) {
    int t = blockIdx.x * blockDim.x + threadIdx.x;   // N_NODES*32 threads
    int n = t >> 5;
    int v = t & 31;
    const float4* s = (const float4*)(emb + (size_t)idx[n] * DIM);
    float4*       d = (float4*)(x + (size_t)n * DIM);
    d[v] = s[v];
}

// ---------------- Wf[r,i,col] = sum_b comp[r,b]*bases[b,i,col] ----------------
__global__ void weights_kernel(const float* __restrict__ comp,
                               const float* __restrict__ bases,
                               float* __restrict__ Wf) {
    int t = blockIdx.x * blockDim.x + threadIdx.x;   // R*DIM*DIM threads
    int col = t & (DIM - 1);
    int row = t >> 7;               // r*DIM + i
    int r = row >> 7, i = row & (DIM - 1);
    float acc = 0.f;
    #pragma unroll
    for (int b = 0; b < N_BASES; ++b)
        acc += comp[r * N_BASES + b] * bases[((size_t)b * DIM + i) * DIM + col];
    Wf[t] = acc;
}

// ---------------- root GEMM: y[N,128] = x[N,128] @ root[128,128] + bias ----------------
__launch_bounds__(256)
__global__ void root_gemm_kernel(const float* __restrict__ x,
                                 const float* __restrict__ root,
                                 const float* __restrict__ bias,
                                 float* __restrict__ y) {
    __shared__ float As[64][33];
    __shared__ float Bs[32][DIM];
    int row0 = blockIdx.x * 64;
    int t = threadIdx.x, tr = t >> 4, tc = t & 15;
    float acc[4][8] = {};
    for (int k0 = 0; k0 < DIM; k0 += 32) {
        #pragma unroll
        for (int i = 0; i < 2; ++i) {
            int li = t + i * 256, r_ = li >> 3, v = li & 7;
            int row = row0 + r_;
            float4 val = make_float4(0.f, 0.f, 0.f, 0.f);
            if (row < N_NODES) val = *(const float4*)(x + (size_t)row * DIM + k0 + v * 4);
            As[r_][v * 4 + 0] = val.x; As[r_][v * 4 + 1] = val.y;
            As[r_][v * 4 + 2] = val.z; As[r_][v * 4 + 3] = val.w;
        }
        #pragma unroll
        for (int i = 0; i < 4; ++i) {
            int li = t + i * 256, rr = li >> 5, v = li & 31;
            *(float4*)(&Bs[rr][v * 4]) = *(const float4*)(root + (size_t)(k0 + rr) * DIM + v * 4);
        }
        __syncthreads();
        #pragma unroll
        for (int k = 0; k < 32; ++k) {
            float a[4], b[8];
            #pragma unroll
            for (int i = 0; i < 4; ++i) a[i] = As[tr * 4 + i][k];
            #pragma unroll
            for (int j = 0; j < 8; ++j) b[j] = Bs[k][tc * 8 + j];
            #pragma unroll
            for (int i = 0; i < 4; ++i)
                #pragma unroll
                for (int j = 0; j < 8; ++j)
                    acc[i][j] += a[i] * b[j];
        }
        __syncthreads();
    }
    #pragma unroll
    for (int i = 0; i < 4; ++i) {
        int row = row0 + tr * 4 + i;
        if (row < N_NODES) {
            #pragma unroll
            for (int j = 0; j < 8; ++j)
                y[(size_t)row * DIM + tc * 8 + j] = acc[i][j] + bias[tc * 8 + j];
        }
    }
}

// ---------------- fused edge GEMM+scatter:
//   y[dst_e,:] += (x[src_e,:] @ W[r]) * (1/c[dst_e,r])  for 64 same-relation edges/block
__launch_bounds__(256)
__global__ void edge_gemm_kernel(const int* __restrict__ srcs, const int* __restrict__ dsts,
                                 const int* __restrict__ off, const float* __restrict__ finv,
                                 const float* __restrict__ x, const float* __restrict__ Wf,
                                 float* __restrict__ y) {
    __shared__ float As[EB][33];
    __shared__ float Bs[32][DIM];
    __shared__ int   sSrc[EB];
    __shared__ int   sDst[EB];
    __shared__ float sScale[EB];
    __shared__ int   soff[R_REL + 1];
    int t = threadIdx.x;
    if (t <= R_REL) soff[t] = off[t];
    __syncthreads();
    int e0 = blockIdx.x * EB;
    if (e0 >= soff[R_REL]) return;          // beyond padded total (uniform exit)
    int r = 0;
    while (e0 >= soff[r + 1]) ++r;          // block's relation (uniform)
    if (t < EB) {
        int s = srcs[e0 + t];
        int d = dsts[e0 + t];
        sSrc[t] = s;
        sDst[t] = d;
        sScale[t] = (s >= 0) ? finv[d * R_REL + r] : 0.0f;
    }
    __syncthreads();
    int tr = t >> 4, tc = t & 15;
    float acc[4][8] = {};
    const float* Wr = Wf + (size_t)r * DIM * DIM;
    for (int k0 = 0; k0 < DIM; k0 += 32) {
        #pragma unroll
        for (int i = 0; i < 2; ++i) {
            int li = t + i * 256, r_ = li >> 3, v = li & 7;
            int s = sSrc[r_];
            float4 val = make_float4(0.f, 0.f, 0.f, 0.f);
            if (s >= 0) val = *(const float4*)(x + (size_t)s * DIM + k0 + v * 4);
            As[r_][v * 4 + 0] = val.x; As[r_][v * 4 + 1] = val.y;
            As[r_][v * 4 + 2] = val.z; As[r_][v * 4 + 3] = val.w;
        }
        #pragma unroll
        for (int i = 0; i < 4; ++i) {
            int li = t + i * 256, rr = li >> 5, v = li & 31;
            *(float4*)(&Bs[rr][v * 4]) = *(const float4*)(Wr + (size_t)(k0 + rr) * DIM + v * 4);
        }
        __syncthreads();
        #pragma unroll
        for (int k = 0; k < 32; ++k) {
            float a[4], b[8];
            #pragma unroll
            for (int i = 0; i < 4; ++i) a[i] = As[tr * 4 + i][k];
            #pragma unroll
            for (int j = 0; j < 8; ++j) b[j] = Bs[k][tc * 8 + j];
            #pragma unroll
            for (int i = 0; i < 4; ++i)
                #pragma unroll
                for (int j = 0; j < 8; ++j)
                    acc[i][j] += a[i] * b[j];
        }
        __syncthreads();
    }
    #pragma unroll
    for (int i = 0; i < 4; ++i) {
        int e = tr * 4 + i;
        float sc = sScale[e];
        if (sc != 0.0f) {
            float* yr = y + (size_t)sDst[e] * DIM + tc * 8;
            #pragma unroll
            for (int j = 0; j < 8; ++j)
                atomicAdd(&yr[j], acc[i][j] * sc);
        }
    }
}

extern "C" void kernel_launch(void* const* d_in, const int* in_sizes, int n_in,
                              void* d_out, int out_size, void* d_ws, size_t ws_size,
                              hipStream_t stream) {
    const int*   node_index = (const int*)d_in[0];
    const int*   edge_index = (const int*)d_in[1];
    const int*   edge_type  = (const int*)d_in[2];
    // d_in[3] node_frequency: unused
    const float* node_emb   = (const float*)d_in[4];
    const float* comp0  = (const float*)d_in[5];
    const float* bases0 = (const float*)d_in[6];
    const float* root0  = (const float*)d_in[7];
    const float* bias0  = (const float*)d_in[8];
    const float* comp1  = (const float*)d_in[9];
    const float* bases1 = (const float*)d_in[10];
    const float* root1  = (const float*)d_in[11];
    const float* bias1  = (const float*)d_in[12];
    float* out = (float*)d_out;

    // ---- workspace layout (all offsets 256B-aligned); total ~32.1 MB ----
    char* ws = (char*)d_ws;
    int*   c_cnt = (int*)(ws);                            //  3,200,000 B
    float* finv  = (float*)(ws + 3200000);                //  3,200,000 B
    float* Wf    = (float*)(ws + 6400000);                //  2,621,440 B
    float* x0    = (float*)(ws + 9021440);                // 10,240,000 B
    float* y0    = (float*)(ws + 19261440);               // 10,240,000 B
    int*   srcs  = (int*)(ws + 29501440);                 //  1,290,240 B
    int*   dsts  = (int*)(ws + 30791680);                 //  1,290,240 B
    int*   meta  = (int*)(ws + 32081920);                 //  off[41] h[40] cur[40]
    int* off = meta;
    int* h   = meta + 64;
    int* cur = meta + 128;

    // ---- build graph structures (shared by both layers) ----
    zero_kernel<<<(N_NODES * R_REL + 255) / 256, 256, 0, stream>>>(c_cnt, N_NODES * R_REL);
    zero_kernel<<<1, 256, 0, stream>>>(meta, 192);
    count_kernel<<<(N_EDGES + 255) / 256, 256, 0, stream>>>(edge_index, edge_type, c_cnt, h);
    inv_kernel<<<(N_NODES * R_REL + 255) / 256, 256, 0, stream>>>(c_cnt, finv);
    scan_kernel<<<1, 64, 0, stream>>>(h, off);
    fill_kernel<<<(P_MAX + 255) / 256, 256, 0, stream>>>(srcs, dsts);
    place_kernel<<<(N_EDGES + 255) / 256, 256, 0, stream>>>(edge_index, edge_type, off, cur, srcs, dsts);
    gather_kernel<<<N_NODES * 32 / 256, 256, 0, stream>>>(node_emb, node_index, x0);

    const int wBlocks = R_REL * DIM * DIM / 256;          // 2560
    const int gBlocks = (N_NODES + 63) / 64;              // 313
    const int eBlocks = P_MAX / EB;                       // 5040

    // ---- layer 0 ----
    weights_kernel<<<wBlocks, 256, 0, stream>>>(comp0, bases0, Wf);
    root_gemm_kernel<<<gBlocks, 256, 0, stream>>>(x0, root0, bias0, y0);
    edge_gemm_kernel<<<eBlocks, 256, 0, stream>>>(srcs, dsts, off, finv, x0, Wf, y0);

    // ---- layer 1 ----
    weights_kernel<<<wBlocks, 256, 0, stream>>>(comp1, bases1, Wf);
    root_gemm_kernel<<<gBlocks, 256, 0, stream>>>(y0, root1, bias1, out);
    edge_gemm_kernel<<<eBlocks, 256, 0, stream>>>(srcs, dsts, off, finv, y0, Wf, out);
}

// Round 4
// 596.224 us; speedup vs baseline: 5.6969x; 5.6969x over previous
//
#include <hip/hip_runtime.h>

#define N_NODES  20000
#define N_EDGES  320000
#define R_REL    40
#define N_BASES  34
#define DIM      128
#define EB       64                       // edges per block (edge GEMM tile M)
#define P_MAX    (N_EDGES + R_REL * EB)   // 322560 max padded sorted edges

typedef unsigned int uint;
typedef unsigned short ushort;

__device__ __forceinline__ ushort f2bf(float f) {   // RNE fp32 -> bf16
    uint u = __float_as_uint(f);
    return (ushort)((u + 0x7FFFu + ((u >> 16) & 1u)) >> 16);
}

// ---------------- utility: zero int buffer ----------------
__global__ void zero_kernel(int* __restrict__ p, int n) {
    int i = blockIdx.x * blockDim.x + threadIdx.x;
    if (i < n) p[i] = 0;
}

// ---------------- fill padded edge slots with sentinel ----------------
__global__ void fill_kernel(int* __restrict__ srcs, float* __restrict__ escale) {
    int i = blockIdx.x * blockDim.x + threadIdx.x;
    if (i < P_MAX) { srcs[i] = -1; escale[i] = 0.0f; }
}

// ---------------- counts c[dst*R+et], relation hist h, dst degree ----------------
__global__ void count_kernel(const int* __restrict__ ei, const int* __restrict__ et,
                             int* __restrict__ c, int* __restrict__ h,
                             int* __restrict__ deg) {
    __shared__ int hloc[R_REL];
    int t = threadIdx.x;
    if (t < R_REL) hloc[t] = 0;
    __syncthreads();
    int e = blockIdx.x * blockDim.x + t;
    if (e < N_EDGES) {
        int dst = ei[N_EDGES + e];
        int r   = et[e];
        atomicAdd(&c[dst * R_REL + r], 1);
        atomicAdd(&deg[dst], 1);
        atomicAdd(&hloc[r], 1);           // LDS atomic (cheap)
    }
    __syncthreads();
    if (t < R_REL && hloc[t]) atomicAdd(&h[t], hloc[t]);   // 40/block global
}

// ---------------- finv = 1/max(c,1) ----------------
__global__ void inv_kernel(const int* __restrict__ c, float* __restrict__ finv) {
    int i = blockIdx.x * blockDim.x + threadIdx.x;
    if (i < N_NODES * R_REL) {
        int v = c[i];
        finv[i] = 1.0f / (float)(v < 1 ? 1 : v);
    }
}

// ---------------- padded exclusive scan of relation histogram ----------------
__global__ void scan_kernel(const int* __restrict__ h, int* __restrict__ off) {
    if (threadIdx.x == 0) {
        int acc = 0;
        off[0] = 0;
        for (int r = 0; r < R_REL; ++r) {
            acc += ((h[r] + EB - 1) / EB) * EB;
            off[r + 1] = acc;
        }
    }
}

// ---------------- exclusive scan of deg -> ptr (dst CSR), single block ----------------
__global__ void scanptr_kernel(const int* __restrict__ deg, int* __restrict__ ptr) {
    __shared__ int part[256];
    const int CH = (N_NODES + 255) / 256;      // 79
    int t = threadIdx.x;
    int s = 0;
    for (int i = 0; i < CH; ++i) {
        int idx = t * CH + i;
        if (idx < N_NODES) s += deg[idx];
    }
    part[t] = s;
    __syncthreads();
    for (int d = 1; d < 256; d <<= 1) {
        int v = (t >= d) ? part[t - d] : 0;
        __syncthreads();
        part[t] += v;
        __syncthreads();
    }
    int base = (t > 0) ? part[t - 1] : 0;
    for (int i = 0; i < CH; ++i) {
        int idx = t * CH + i;
        if (idx < N_NODES) { ptr[idx] = base; base += deg[idx]; }
    }
    if (t == 255) ptr[N_NODES] = N_EDGES;
}

// ---------------- placement: relation-sorted padded slots + dst-CSR edge list ----------------
__global__ void place_kernel(const int* __restrict__ ei, const int* __restrict__ et,
                             const int* __restrict__ off, int* __restrict__ cur,
                             const float* __restrict__ finv,
                             const int* __restrict__ ptr, int* __restrict__ cur2,
                             int* __restrict__ srcs, float* __restrict__ escale,
                             int* __restrict__ ebyd) {
    __shared__ int hloc[R_REL];
    __shared__ int base[R_REL];
    int t = threadIdx.x;
    if (t < R_REL) hloc[t] = 0;
    __syncthreads();
    int e = blockIdx.x * blockDim.x + t;
    int r = 0, myrank = 0, src = 0, dst = 0;
    bool valid = (e < N_EDGES);
    if (valid) {
        r = et[e]; src = ei[e]; dst = ei[N_EDGES + e];
        myrank = atomicAdd(&hloc[r], 1);      // LDS
    }
    __syncthreads();
    if (t < R_REL) base[t] = hloc[t] ? atomicAdd(&cur[t], hloc[t]) : 0;
    __syncthreads();
    if (valid) {
        int p = off[r] + base[r] + myrank;
        srcs[p]   = src;
        escale[p] = finv[dst * R_REL + r];
        int q = ptr[dst] + atomicAdd(&cur2[dst], 1);
        ebyd[q] = p;
    }
}

// ---------------- gather: x0[n,:] = node_emb[node_index[n],:] ----------------
__global__ void gather_kernel(const float* __restrict__ emb,
                              const int* __restrict__ idx,
                              float* __restrict__ x) {
    int t = blockIdx.x * blockDim.x + threadIdx.x;   // N_NODES*32 threads
    int n = t >> 5;
    int v = t & 31;
    const float4* s = (const float4*)(emb + (size_t)idx[n] * DIM);
    float4*       d = (float4*)(x + (size_t)n * DIM);
    d[v] = s[v];
}

// ---------------- Wf[r,i,col] = sum_b comp[r,b]*bases[b,i,col] ----------------
__global__ void weights_kernel(const float* __restrict__ comp,
                               const float* __restrict__ bases,
                               float* __restrict__ Wf) {
    int t = blockIdx.x * blockDim.x + threadIdx.x;   // R*DIM*DIM threads
    int col = t & (DIM - 1);
    int row = t >> 7;               // r*DIM + i
    int r = row >> 7, i = row & (DIM - 1);
    float acc = 0.f;
    #pragma unroll
    for (int b = 0; b < N_BASES; ++b)
        acc += comp[r * N_BASES + b] * bases[((size_t)b * DIM + i) * DIM + col];
    Wf[t] = acc;
}

// ---------------- root GEMM: y[N,128] = x[N,128] @ root[128,128] + bias ----------------
__launch_bounds__(256)
__global__ void root_gemm_kernel(const float* __restrict__ x,
                                 const float* __restrict__ root,
                                 const float* __restrict__ bias,
                                 float* __restrict__ y) {
    __shared__ float As[64][33];
    __shared__ float Bs[32][DIM];
    int row0 = blockIdx.x * 64;
    int t = threadIdx.x, tr = t >> 4, tc = t & 15;
    float acc[4][8] = {};
    for (int k0 = 0; k0 < DIM; k0 += 32) {
        #pragma unroll
        for (int i = 0; i < 2; ++i) {
            int li = t + i * 256, r_ = li >> 3, v = li & 7;
            int row = row0 + r_;
            float4 val = make_float4(0.f, 0.f, 0.f, 0.f);
            if (row < N_NODES) val = *(const float4*)(x + (size_t)row * DIM + k0 + v * 4);
            As[r_][v * 4 + 0] = val.x; As[r_][v * 4 + 1] = val.y;
            As[r_][v * 4 + 2] = val.z; As[r_][v * 4 + 3] = val.w;
        }
        #pragma unroll
        for (int i = 0; i < 4; ++i) {
            int li = t + i * 256, rr = li >> 5, v = li & 31;
            *(float4*)(&Bs[rr][v * 4]) = *(const float4*)(root + (size_t)(k0 + rr) * DIM + v * 4);
        }
        __syncthreads();
        #pragma unroll
        for (int k = 0; k < 32; ++k) {
            float a[4], b[8];
            #pragma unroll
            for (int i = 0; i < 4; ++i) a[i] = As[tr * 4 + i][k];
            #pragma unroll
            for (int j = 0; j < 8; ++j) b[j] = Bs[k][tc * 8 + j];
            #pragma unroll
            for (int i = 0; i < 4; ++i)
                #pragma unroll
                for (int j = 0; j < 8; ++j)
                    acc[i][j] += a[i] * b[j];
        }
        __syncthreads();
    }
    #pragma unroll
    for (int i = 0; i < 4; ++i) {
        int row = row0 + tr * 4 + i;
        if (row < N_NODES) {
            #pragma unroll
            for (int j = 0; j < 8; ++j)
                y[(size_t)row * DIM + tc * 8 + j] = acc[i][j] + bias[tc * 8 + j];
        }
    }
}

// ---------------- edge GEMM: T[p,:] = bf16( (x[src_p,:] @ W[r]) * escale[p] ) ----------------
__launch_bounds__(256)
__global__ void edge_gemm_kernel(const int* __restrict__ srcs, const float* __restrict__ escale,
                                 const int* __restrict__ off,
                                 const float* __restrict__ x, const float* __restrict__ Wf,
                                 ushort* __restrict__ T) {
    __shared__ float As[EB][33];
    __shared__ float Bs[32][DIM];
    __shared__ int   sSrc[EB];
    __shared__ float sScale[EB];
    __shared__ int   soff[R_REL + 1];
    int t = threadIdx.x;
    if (t <= R_REL) soff[t] = off[t];
    __syncthreads();
    int e0 = blockIdx.x * EB;
    if (e0 >= soff[R_REL]) return;          // beyond padded total (uniform exit)
    int r = 0;
    while (e0 >= soff[r + 1]) ++r;          // block's relation (uniform)
    if (t < EB) {
        sSrc[t]   = srcs[e0 + t];
        sScale[t] = escale[e0 + t];
    }
    __syncthreads();
    int tr = t >> 4, tc = t & 15;
    float acc[4][8] = {};
    const float* Wr = Wf + (size_t)r * DIM * DIM;
    for (int k0 = 0; k0 < DIM; k0 += 32) {
        #pragma unroll
        for (int i = 0; i < 2; ++i) {
            int li = t + i * 256, r_ = li >> 3, v = li & 7;
            int s = sSrc[r_];
            float4 val = make_float4(0.f, 0.f, 0.f, 0.f);
            if (s >= 0) val = *(const float4*)(x + (size_t)s * DIM + k0 + v * 4);
            As[r_][v * 4 + 0] = val.x; As[r_][v * 4 + 1] = val.y;
            As[r_][v * 4 + 2] = val.z; As[r_][v * 4 + 3] = val.w;
        }
        #pragma unroll
        for (int i = 0; i < 4; ++i) {
            int li = t + i * 256, rr = li >> 5, v = li & 31;
            *(float4*)(&Bs[rr][v * 4]) = *(const float4*)(Wr + (size_t)(k0 + rr) * DIM + v * 4);
        }
        __syncthreads();
        #pragma unroll
        for (int k = 0; k < 32; ++k) {
            float a[4], b[8];
            #pragma unroll
            for (int i = 0; i < 4; ++i) a[i] = As[tr * 4 + i][k];
            #pragma unroll
            for (int j = 0; j < 8; ++j) b[j] = Bs[k][tc * 8 + j];
            #pragma unroll
            for (int i = 0; i < 4; ++i)
                #pragma unroll
                for (int j = 0; j < 8; ++j)
                    acc[i][j] += a[i] * b[j];
        }
        __syncthreads();
    }
    #pragma unroll
    for (int i = 0; i < 4; ++i) {
        int e = tr * 4 + i;
        float sc = sScale[e];
        if (sc != 0.0f) {
            uint4 pk;
            pk.x = (uint)f2bf(acc[i][0] * sc) | ((uint)f2bf(acc[i][1] * sc) << 16);
            pk.y = (uint)f2bf(acc[i][2] * sc) | ((uint)f2bf(acc[i][3] * sc) << 16);
            pk.z = (uint)f2bf(acc[i][4] * sc) | ((uint)f2bf(acc[i][5] * sc) << 16);
            pk.w = (uint)f2bf(acc[i][6] * sc) | ((uint)f2bf(acc[i][7] * sc) << 16);
            *(uint4*)(T + (size_t)(e0 + e) * DIM + tc * 8) = pk;
        }
    }
}

// ---------------- aggregate: y[n,:] += sum over incoming edges of T[p,:] ----------------
__global__ void aggregate_kernel(const int* __restrict__ ptr, const int* __restrict__ ebyd,
                                 const ushort* __restrict__ T, float* __restrict__ y) {
    int n = blockIdx.x;          // one block (128 threads) per node
    int col = threadIdx.x;
    int s0 = ptr[n], s1 = ptr[n + 1];
    float acc = 0.f;
    for (int q = s0; q < s1; ++q) {
        int p = ebyd[q];
        acc += __uint_as_float(((uint)T[(size_t)p * DIM + col]) << 16);
    }
    y[(size_t)n * DIM + col] += acc;
}

extern "C" void kernel_launch(void* const* d_in, const int* in_sizes, int n_in,
                              void* d_out, int out_size, void* d_ws, size_t ws_size,
                              hipStream_t stream) {
    const int*   node_index = (const int*)d_in[0];
    const int*   edge_index = (const int*)d_in[1];
    const int*   edge_type  = (const int*)d_in[2];
    // d_in[3] node_frequency: unused
    const float* node_emb   = (const float*)d_in[4];
    const float* comp0  = (const float*)d_in[5];
    const float* bases0 = (const float*)d_in[6];
    const float* root0  = (const float*)d_in[7];
    const float* bias0  = (const float*)d_in[8];
    const float* comp1  = (const float*)d_in[9];
    const float* bases1 = (const float*)d_in[10];
    const float* root1  = (const float*)d_in[11];
    const float* bias1  = (const float*)d_in[12];
    float* out = (float*)d_out;

    // ---- workspace layout (~116 MB) ----
    char* ws = (char*)d_ws;
    int*    c_cnt  = (int*)   (ws);                 //  3,200,000 B
    float*  finv   = (float*) (ws + 3200000);       //  3,200,000 B
    float*  Wf     = (float*) (ws + 6400000);       //  2,621,440 B
    float*  x0     = (float*) (ws + 9021440);       // 10,240,000 B
    float*  y0     = (float*) (ws + 19261440);      // 10,240,000 B
    int*    srcs   = (int*)   (ws + 29501440);      //  1,290,240 B
    float*  escale = (float*) (ws + 30791680);      //  1,290,240 B
    int*    ebyd   = (int*)   (ws + 32081920);      //  1,280,000 B
    int*    meta   = (int*)   (ws + 33361920);      //  1,024 B: off[41] h[40] cur[40]
    int*    deg    = (int*)   (ws + 33362944);      //  80,000 B
    int*    cur2   = (int*)   (ws + 33442944);      //  80,000 B
    int*    ptr    = (int*)   (ws + 33522944);      //  80,128 B (20001 ints)
    ushort* T      = (ushort*)(ws + 33603328);      // 82,575,360 B
    int* off = meta;
    int* h   = meta + 64;
    int* cur = meta + 128;

    // ---- build graph structures (shared by both layers) ----
    zero_kernel<<<(N_NODES * R_REL + 255) / 256, 256, 0, stream>>>(c_cnt, N_NODES * R_REL);
    zero_kernel<<<(256 + 20000 + 20000 + 255) / 256, 256, 0, stream>>>(meta, 256 + 20000 + 20000); // meta+deg+cur2 (contiguous)
    count_kernel<<<(N_EDGES + 255) / 256, 256, 0, stream>>>(edge_index, edge_type, c_cnt, h, deg);
    inv_kernel<<<(N_NODES * R_REL + 255) / 256, 256, 0, stream>>>(c_cnt, finv);
    scan_kernel<<<1, 64, 0, stream>>>(h, off);
    scanptr_kernel<<<1, 256, 0, stream>>>(deg, ptr);
    fill_kernel<<<(P_MAX + 255) / 256, 256, 0, stream>>>(srcs, escale);
    place_kernel<<<(N_EDGES + 255) / 256, 256, 0, stream>>>(edge_index, edge_type, off, cur,
                                                            finv, ptr, cur2, srcs, escale, ebyd);
    gather_kernel<<<N_NODES * 32 / 256, 256, 0, stream>>>(node_emb, node_index, x0);

    const int wBlocks = R_REL * DIM * DIM / 256;          // 2560
    const int gBlocks = (N_NODES + 63) / 64;              // 313
    const int eBlocks = P_MAX / EB;                       // 5040

    // ---- layer 0 ----
    weights_kernel<<<wBlocks, 256, 0, stream>>>(comp0, bases0, Wf);
    root_gemm_kernel<<<gBlocks, 256, 0, stream>>>(x0, root0, bias0, y0);
    edge_gemm_kernel<<<eBlocks, 256, 0, stream>>>(srcs, escale, off, x0, Wf, T);
    aggregate_kernel<<<N_NODES, DIM, 0, stream>>>(ptr, ebyd, T, y0);

    // ---- layer 1 ----
    weights_kernel<<<wBlocks, 256, 0, stream>>>(comp1, bases1, Wf);
    root_gemm_kernel<<<gBlocks, 256, 0, stream>>>(y0, root1, bias1, out);
    edge_gemm_kernel<<<eBlocks, 256, 0, stream>>>(srcs, escale, off, y0, Wf, T);
    aggregate_kernel<<<N_NODES, DIM, 0, stream>>>(ptr, ebyd, T, out);
}

// Round 5
// 393.155 us; speedup vs baseline: 8.6394x; 1.5165x over previous
//
#include <hip/hip_runtime.h>

#define N_NODES  20000
#define N_EDGES  320000
#define R_REL    40
#define N_BASES  34
#define DIM      128
#define EB       64                          // edges per block (edge GEMM tile M)
#define P_PAD    (N_EDGES + R_REL * EB)      // 322560: worst-case padded relation edges
#define ROOT_PAD ((N_NODES + EB - 1) / EB * EB)  // 20032
#define P2_MAX   (P_PAD + ROOT_PAD)          // 342592 (root edges = slot 40)
#define NE2      (N_EDGES + N_NODES)         // dst-CSR entries incl. root edges

typedef unsigned int uint;
typedef unsigned short ushort;
typedef __attribute__((ext_vector_type(8))) short short8;   // 8 bf16 = 4 VGPRs
typedef __attribute__((ext_vector_type(4))) float f32x4;

__device__ __forceinline__ ushort f2bf(float f) {   // RNE fp32 -> bf16
    uint u = __float_as_uint(f);
    return (ushort)((u + 0x7FFFu + ((u >> 16) & 1u)) >> 16);
}
__device__ __forceinline__ uint pk2bf(float a, float b) {
    return (uint)f2bf(a) | ((uint)f2bf(b) << 16);
}

// ---------------- utility: zero int buffer ----------------
__global__ void zero_kernel(int* __restrict__ p, int n) {
    int i = blockIdx.x * blockDim.x + threadIdx.x;
    if (i < n) p[i] = 0;
}

// ---------------- fill padded edge slots with sentinel ----------------
__global__ void fill_kernel(int* __restrict__ srcs, float* __restrict__ escale) {
    int i = blockIdx.x * blockDim.x + threadIdx.x;
    if (i < P2_MAX) { srcs[i] = -1; escale[i] = 0.0f; }
}

// ---------------- counts c[dst*R+et], relation hist h, dst degree ----------------
__global__ void count_kernel(const int* __restrict__ ei, const int* __restrict__ et,
                             int* __restrict__ c, int* __restrict__ h,
                             int* __restrict__ deg) {
    __shared__ int hloc[R_REL];
    int t = threadIdx.x;
    if (t < R_REL) hloc[t] = 0;
    __syncthreads();
    int e = blockIdx.x * blockDim.x + t;
    if (e < N_EDGES) {
        int dst = ei[N_EDGES + e];
        int r   = et[e];
        atomicAdd(&c[dst * R_REL + r], 1);
        atomicAdd(&deg[dst], 1);
        atomicAdd(&hloc[r], 1);
    }
    __syncthreads();
    if (t < R_REL && hloc[t]) atomicAdd(&h[t], hloc[t]);
}

// ---------------- finv = 1/max(c,1) ----------------
__global__ void inv_kernel(const int* __restrict__ c, float* __restrict__ finv) {
    int i = blockIdx.x * blockDim.x + threadIdx.x;
    if (i < N_NODES * R_REL) {
        int v = c[i];
        finv[i] = 1.0f / (float)(v < 1 ? 1 : v);
    }
}

// ---------------- padded exclusive scan of relation histogram; slot 40 = root ----------------
__global__ void scan_kernel(const int* __restrict__ h, int* __restrict__ off) {
    if (threadIdx.x == 0) {
        int acc = 0;
        off[0] = 0;
        for (int r = 0; r < R_REL; ++r) {
            acc += ((h[r] + EB - 1) / EB) * EB;
            off[r + 1] = acc;
        }
        off[R_REL + 1] = acc + ROOT_PAD;
    }
}

// ---------------- exclusive scan of (deg+1) -> ptr (dst CSR incl. root slot) ----------------
__global__ void scanptr_kernel(const int* __restrict__ deg, int* __restrict__ ptr) {
    __shared__ int part[256];
    const int CH = (N_NODES + 255) / 256;      // 79
    int t = threadIdx.x;
    int s = 0;
    for (int i = 0; i < CH; ++i) {
        int idx = t * CH + i;
        if (idx < N_NODES) s += deg[idx] + 1;
    }
    part[t] = s;
    __syncthreads();
    for (int d = 1; d < 256; d <<= 1) {
        int v = (t >= d) ? part[t - d] : 0;
        __syncthreads();
        part[t] += v;
        __syncthreads();
    }
    int base = (t > 0) ? part[t - 1] : 0;
    for (int i = 0; i < CH; ++i) {
        int idx = t * CH + i;
        if (idx < N_NODES) { ptr[idx] = base; base += deg[idx] + 1; }
    }
    if (t == 255) ptr[N_NODES] = NE2;
}

// ---------------- placement of real edges (root slot 0 of each CSR segment reserved) ----------------
__global__ void place_kernel(const int* __restrict__ ei, const int* __restrict__ et,
                             const int* __restrict__ off, int* __restrict__ cur,
                             const float* __restrict__ finv,
                             const int* __restrict__ ptr, int* __restrict__ cur2,
                             int* __restrict__ srcs, float* __restrict__ escale,
                             int* __restrict__ ebyd) {
    __shared__ int hloc[R_REL];
    __shared__ int base[R_REL];
    int t = threadIdx.x;
    if (t < R_REL) hloc[t] = 0;
    __syncthreads();
    int e = blockIdx.x * blockDim.x + t;
    int r = 0, myrank = 0, src = 0, dst = 0;
    bool valid = (e < N_EDGES);
    if (valid) {
        r = et[e]; src = ei[e]; dst = ei[N_EDGES + e];
        myrank = atomicAdd(&hloc[r], 1);
    }
    __syncthreads();
    if (t < R_REL) base[t] = hloc[t] ? atomicAdd(&cur[t], hloc[t]) : 0;
    __syncthreads();
    if (valid) {
        int p = off[r] + base[r] + myrank;
        srcs[p]   = src;
        escale[p] = finv[dst * R_REL + r];
        int q = ptr[dst] + 1 + atomicAdd(&cur2[dst], 1);
        ebyd[q] = p;
    }
}

// ---------------- root edges: slot 40, scale 1, first CSR slot of each node ----------------
__global__ void rootplace_kernel(const int* __restrict__ off, const int* __restrict__ ptr,
                                 int* __restrict__ srcs, float* __restrict__ escale,
                                 int* __restrict__ ebyd) {
    int n = blockIdx.x * blockDim.x + threadIdx.x;
    if (n >= N_NODES) return;
    int p = off[R_REL] + n;
    srcs[p]   = n;
    escale[p] = 1.0f;
    ebyd[ptr[n]] = p;
}

// ---------------- gather + bf16 convert: xb[n,:] = bf16(node_emb[node_index[n],:]) ----------------
__global__ void gather_bf16_kernel(const float* __restrict__ emb, const int* __restrict__ idx,
                                   ushort* __restrict__ xb) {
    int t = blockIdx.x * blockDim.x + threadIdx.x;   // N_NODES*16 threads
    int n = t >> 4, v = t & 15;
    const float4* s = (const float4*)(emb + (size_t)idx[n] * DIM + v * 8);
    float4 a = s[0], b = s[1];
    uint4 o;
    o.x = pk2bf(a.x, a.y); o.y = pk2bf(a.z, a.w);
    o.z = pk2bf(b.x, b.y); o.w = pk2bf(b.z, b.w);
    *(uint4*)(xb + (size_t)n * DIM + v * 8) = o;
}

// ---------------- Wf[r,k,n] = sum_b comp[r,b]*bases[b,k,n]  (f32, coalesced) ----------------
__global__ void weights_kernel(const float* __restrict__ comp,
                               const float* __restrict__ bases,
                               float* __restrict__ Wf) {
    int t = blockIdx.x * blockDim.x + threadIdx.x;   // R*DIM*DIM threads
    int col = t & (DIM - 1);
    int row = t >> 7;               // r*DIM + k
    int r = row >> 7, i = row & (DIM - 1);
    float acc = 0.f;
    #pragma unroll
    for (int b = 0; b < N_BASES; ++b)
        acc += comp[r * N_BASES + b] * bases[((size_t)b * DIM + i) * DIM + col];
    Wf[t] = acc;
}

// ---------------- transpose-convert: Wt[slot][n][k] = bf16(W[slot][k][n]); slot 40 = root ----------------
__global__ void transW_kernel(const float* __restrict__ Wf, const float* __restrict__ root,
                              ushort* __restrict__ Wt) {
    __shared__ float tile[32][33];
    int slot = blockIdx.x >> 4;
    int tb   = blockIdx.x & 15;
    int k0 = (tb >> 2) * 32, n0 = (tb & 3) * 32;
    const float* srcp = (slot < R_REL) ? (Wf + (size_t)slot * DIM * DIM) : root;
    int t = threadIdx.x;
    int tr = t >> 5, tc = t & 31;
    #pragma unroll
    for (int i = 0; i < 4; ++i)
        tile[tr + 8 * i][tc] = srcp[(size_t)(k0 + tr + 8 * i) * DIM + n0 + tc];
    __syncthreads();
    #pragma unroll
    for (int i = 0; i < 4; ++i) {
        int rr = tr + 8 * i;
        Wt[(size_t)slot * DIM * DIM + (size_t)(n0 + rr) * DIM + k0 + tc] = f2bf(tile[tc][rr]);
    }
}

// ---------------- MFMA edge GEMM: T[p][n] = bf16( (x[src_p] @ W[r])[n] * escale[p] )
//   computed as D = Wt_slice(16n x 32k) . X^T_slice(32k x 16e) per 16x16x32 MFMA.
__launch_bounds__(256)
__global__ void edge_mfma_kernel(const int* __restrict__ srcs, const float* __restrict__ escale,
                                 const int* __restrict__ off,
                                 const ushort* __restrict__ xb, const ushort* __restrict__ Wt,
                                 ushort* __restrict__ T) {
    __shared__ __align__(16) ushort As[EB * DIM];   // 16 KB, 16B-slot XOR swizzled
    __shared__ int soff[R_REL + 2];
    int t = threadIdx.x;
    if (t < R_REL + 2) soff[t] = off[t];
    __syncthreads();
    int e0 = blockIdx.x * EB;
    if (e0 >= soff[R_REL + 1]) return;               // uniform exit
    int r = 0;
    while (e0 >= soff[r + 1]) ++r;                   // block's W slot (0..40, uniform)

    // stage 64 x-rows (bf16, 256B each) into LDS; slot s of row -> s ^ (row&15)
    #pragma unroll
    for (int i = 0; i < 4; ++i) {
        int q = t + 256 * i;
        int row = q >> 4, slot = q & 15;
        int s = srcs[e0 + row];
        uint4 v = make_uint4(0u, 0u, 0u, 0u);
        if (s >= 0) v = *(const uint4*)(xb + (size_t)s * DIM + slot * 8);
        *(uint4*)(&As[row * DIM + ((slot ^ (row & 15)) * 8)]) = v;
    }
    __syncthreads();

    int wv = t >> 6;            // wave 0..3 -> edges 16*wv .. +15
    int l  = t & 63;
    int lr = l & 15;            // edge col (B) / n row (A)
    int lk = l >> 4;            // k sub-segment 0..3

    // B-fragments: x^T, all 4 k-steps (reused across 8 n-tiles)
    short8 xf[4];
    int xrow = wv * 16 + lr;
    #pragma unroll
    for (int ks = 0; ks < 4; ++ks) {
        int slot = ks * 4 + lk;
        xf[ks] = *(const short8*)(&As[xrow * DIM + ((slot ^ (xrow & 15)) * 8)]);
    }

    const ushort* Wr = Wt + (size_t)r * DIM * DIM;
    float esc = escale[e0 + xrow];
    ushort* Trow = T + (size_t)(e0 + xrow) * DIM;

    #pragma unroll
    for (int mt = 0; mt < 8; ++mt) {                 // n-tiles
        f32x4 acc = {0.f, 0.f, 0.f, 0.f};
        #pragma unroll
        for (int ks = 0; ks < 4; ++ks) {
            short8 wf = *(const short8*)(Wr + (size_t)(mt * 16 + lr) * DIM + ks * 32 + lk * 8);
            acc = __builtin_amdgcn_mfma_f32_16x16x32_bf16(wf, xf[ks], acc, 0, 0, 0);
        }
        // lane holds D[n = mt*16 + lk*4 + i][e = xrow], i=0..3 -> 4 contiguous bf16
        uint2 pk;
        pk.x = pk2bf(acc[0] * esc, acc[1] * esc);
        pk.y = pk2bf(acc[2] * esc, acc[3] * esc);
        *(uint2*)(Trow + mt * 16 + lk * 4) = pk;
    }
}

// ---------------- aggregate: y[n,:] = bias + sum over CSR segment of T rows ----------------
template<int OUT_BF16>
__global__ void aggregate_kernel(const int* __restrict__ ptr, const int* __restrict__ ebyd,
                                 const ushort* __restrict__ T, const float* __restrict__ bias,
                                 void* __restrict__ yout) {
    int n = blockIdx.x;          // 64 threads, 2 cols each
    int t = threadIdx.x;
    int s0 = ptr[n], s1 = ptr[n + 1];
    float a0 = bias[2 * t], a1 = bias[2 * t + 1];
    for (int q = s0; q < s1; ++q) {
        int p = ebyd[q];
        uint v = *(const uint*)(T + (size_t)p * DIM + 2 * t);
        a0 += __uint_as_float(v << 16);
        a1 += __uint_as_float(v & 0xFFFF0000u);
    }
    if (OUT_BF16) {
        ((uint*)yout)[n * 64 + t] = pk2bf(a0, a1);
    } else {
        ((float2*)yout)[n * 64 + t] = make_float2(a0, a1);
    }
}

extern "C" void kernel_launch(void* const* d_in, const int* in_sizes, int n_in,
                              void* d_out, int out_size, void* d_ws, size_t ws_size,
                              hipStream_t stream) {
    const int*   node_index = (const int*)d_in[0];
    const int*   edge_index = (const int*)d_in[1];
    const int*   edge_type  = (const int*)d_in[2];
    // d_in[3] node_frequency: unused
    const float* node_emb   = (const float*)d_in[4];
    const float* comp0  = (const float*)d_in[5];
    const float* bases0 = (const float*)d_in[6];
    const float* root0  = (const float*)d_in[7];
    const float* bias0  = (const float*)d_in[8];
    const float* comp1  = (const float*)d_in[9];
    const float* bases1 = (const float*)d_in[10];
    const float* root1  = (const float*)d_in[11];
    const float* bias1  = (const float*)d_in[12];
    float* out = (float*)d_out;

    // ---- workspace layout (~113 MB) ----
    char* ws = (char*)d_ws;
    int*    c_cnt  = (int*)   (ws);                 //  3,200,000
    float*  finv   = (float*) (ws +  3200000);      //  3,200,000
    float*  Wf     = (float*) (ws +  6400000);      //  2,621,440 (40 slots f32)
    ushort* Wt     = (ushort*)(ws +  9021440);      //  1,343,488 (41 slots bf16 [n][k])
    ushort* x0b    = (ushort*)(ws + 10364928);      //  5,120,000
    ushort* y0b    = (ushort*)(ws + 15484928);      //  5,120,000
    int*    srcs   = (int*)   (ws + 20604928);      //  1,370,368 (P2_MAX)
    float*  escale = (float*) (ws + 21975296);      //  1,370,368
    int*    ebyd   = (int*)   (ws + 23345664);      //  1,360,000 (NE2)
    int*    meta   = (int*)   (ws + 24705664);      //  1,024: off[42]@0 h[40]@64 cur[40]@128
    int*    deg    = (int*)   (ws + 24706688);      //  80,000
    int*    cur2   = (int*)   (ws + 24786688);      //  80,000
    int*    ptr    = (int*)   (ws + 24866688);      //  80,256 (20001 ints)
    ushort* T      = (ushort*)(ws + 24946944);      // 87,703,552 (P2_MAX * 128 bf16)
    int* off = meta;
    int* h   = meta + 64;
    int* cur = meta + 128;

    // ---- build graph structures (shared by both layers) ----
    zero_kernel<<<(N_NODES * R_REL + 255) / 256, 256, 0, stream>>>(c_cnt, N_NODES * R_REL);
    zero_kernel<<<(256 + 20000 + 20000 + 255) / 256, 256, 0, stream>>>(meta, 256 + 20000 + 20000);
    count_kernel<<<(N_EDGES + 255) / 256, 256, 0, stream>>>(edge_index, edge_type, c_cnt, h, deg);
    inv_kernel<<<(N_NODES * R_REL + 255) / 256, 256, 0, stream>>>(c_cnt, finv);
    scan_kernel<<<1, 64, 0, stream>>>(h, off);
    scanptr_kernel<<<1, 256, 0, stream>>>(deg, ptr);
    fill_kernel<<<(P2_MAX + 255) / 256, 256, 0, stream>>>(srcs, escale);
    place_kernel<<<(N_EDGES + 255) / 256, 256, 0, stream>>>(edge_index, edge_type, off, cur,
                                                            finv, ptr, cur2, srcs, escale, ebyd);
    rootplace_kernel<<<(N_NODES + 255) / 256, 256, 0, stream>>>(off, ptr, srcs, escale, ebyd);
    gather_bf16_kernel<<<N_NODES * 16 / 256, 256, 0, stream>>>(node_emb, node_index, x0b);

    const int wBlocks = R_REL * DIM * DIM / 256;          // 2560
    const int tBlocks = (R_REL + 1) * 16;                 // 656
    const int eBlocks = P2_MAX / EB;                      // 5353

    // ---- layer 0 ----
    weights_kernel<<<wBlocks, 256, 0, stream>>>(comp0, bases0, Wf);
    transW_kernel<<<tBlocks, 256, 0, stream>>>(Wf, root0, Wt);
    edge_mfma_kernel<<<eBlocks, 256, 0, stream>>>(srcs, escale, off, x0b, Wt, T);
    aggregate_kernel<1><<<N_NODES, 64, 0, stream>>>(ptr, ebyd, T, bias0, y0b);

    // ---- layer 1 ----
    weights_kernel<<<wBlocks, 256, 0, stream>>>(comp1, bases1, Wf);
    transW_kernel<<<tBlocks, 256, 0, stream>>>(Wf, root1, Wt);
    edge_mfma_kernel<<<eBlocks, 256, 0, stream>>>(srcs, escale, off, y0b, Wt, T);
    aggregate_kernel<0><<<N_NODES, 64, 0, stream>>>(ptr, ebyd, T, bias1, out);
}

// Round 6
// 290.555 us; speedup vs baseline: 11.6902x; 1.3531x over previous
//
#include <hip/hip_runtime.h>

#define N_NODES  20000
#define N_EDGES  320000
#define R_REL    40
#define N_BASES  34
#define DIM      128
#define EB       128                         // edges per block (edge GEMM tile M)
#define P_PAD    (N_EDGES + R_REL * EB)      // 325120: worst-case padded relation edges
#define ROOT_PAD ((N_NODES + EB - 1) / EB * EB)  // 20096
#define P2_MAX   (P_PAD + ROOT_PAD)          // 345216 (root edges = slot 40)
#define NE2      (N_EDGES + N_NODES)         // dst-CSR entries incl. root edges

typedef unsigned int uint;
typedef unsigned short ushort;
typedef __attribute__((ext_vector_type(8))) short short8;   // 8 bf16 = 4 VGPRs
typedef __attribute__((ext_vector_type(4))) float f32x4;

__device__ __forceinline__ ushort f2bf(float f) {   // RNE fp32 -> bf16
    uint u = __float_as_uint(f);
    return (ushort)((u + 0x7FFFu + ((u >> 16) & 1u)) >> 16);
}
__device__ __forceinline__ uint pk2bf(float a, float b) {
    return (uint)f2bf(a) | ((uint)f2bf(b) << 16);
}

// ---------------- utility: zero int buffer ----------------
__global__ void zero_kernel(int* __restrict__ p, int n) {
    int i = blockIdx.x * blockDim.x + threadIdx.x;
    if (i < n) p[i] = 0;
}

// ---------------- fill padded edge slots with sentinel ----------------
__global__ void fill_kernel(int* __restrict__ srcs, float* __restrict__ escale) {
    int i = blockIdx.x * blockDim.x + threadIdx.x;
    if (i < P2_MAX) { srcs[i] = -1; escale[i] = 0.0f; }
}

// ---------------- counts c[dst*R+et], relation hist h, dst degree ----------------
__global__ void count_kernel(const int* __restrict__ ei, const int* __restrict__ et,
                             int* __restrict__ c, int* __restrict__ h,
                             int* __restrict__ deg) {
    __shared__ int hloc[R_REL];
    int t = threadIdx.x;
    if (t < R_REL) hloc[t] = 0;
    __syncthreads();
    int e = blockIdx.x * blockDim.x + t;
    if (e < N_EDGES) {
        int dst = ei[N_EDGES + e];
        int r   = et[e];
        atomicAdd(&c[dst * R_REL + r], 1);
        atomicAdd(&deg[dst], 1);
        atomicAdd(&hloc[r], 1);
    }
    __syncthreads();
    if (t < R_REL && hloc[t]) atomicAdd(&h[t], hloc[t]);
}

// ---------------- finv = 1/max(c,1) ----------------
__global__ void inv_kernel(const int* __restrict__ c, float* __restrict__ finv) {
    int i = blockIdx.x * blockDim.x + threadIdx.x;
    if (i < N_NODES * R_REL) {
        int v = c[i];
        finv[i] = 1.0f / (float)(v < 1 ? 1 : v);
    }
}

// ---------------- padded exclusive scan of relation histogram; slot 40 = root ----------------
__global__ void scan_kernel(const int* __restrict__ h, int* __restrict__ off) {
    if (threadIdx.x == 0) {
        int acc = 0;
        off[0] = 0;
        for (int r = 0; r < R_REL; ++r) {
            acc += ((h[r] + EB - 1) / EB) * EB;
            off[r + 1] = acc;
        }
        off[R_REL + 1] = acc + ROOT_PAD;
    }
}

// ---------------- exclusive scan of (deg+1) -> ptr (dst CSR incl. root slot) ----------------
__global__ void scanptr_kernel(const int* __restrict__ deg, int* __restrict__ ptr) {
    __shared__ int part[256];
    const int CH = (N_NODES + 255) / 256;      // 79
    int t = threadIdx.x;
    int s = 0;
    for (int i = 0; i < CH; ++i) {
        int idx = t * CH + i;
        if (idx < N_NODES) s += deg[idx] + 1;
    }
    part[t] = s;
    __syncthreads();
    for (int d = 1; d < 256; d <<= 1) {
        int v = (t >= d) ? part[t - d] : 0;
        __syncthreads();
        part[t] += v;
        __syncthreads();
    }
    int base = (t > 0) ? part[t - 1] : 0;
    for (int i = 0; i < CH; ++i) {
        int idx = t * CH + i;
        if (idx < N_NODES) { ptr[idx] = base; base += deg[idx] + 1; }
    }
    if (t == 255) ptr[N_NODES] = NE2;
}

// ---------------- placement of real edges (root slot 0 of each CSR segment reserved) ----------------
__global__ void place_kernel(const int* __restrict__ ei, const int* __restrict__ et,
                             const int* __restrict__ off, int* __restrict__ cur,
                             const float* __restrict__ finv,
                             const int* __restrict__ ptr, int* __restrict__ cur2,
                             int* __restrict__ srcs, float* __restrict__ escale,
                             int* __restrict__ ebyd) {
    __shared__ int hloc[R_REL];
    __shared__ int base[R_REL];
    int t = threadIdx.x;
    if (t < R_REL) hloc[t] = 0;
    __syncthreads();
    int e = blockIdx.x * blockDim.x + t;
    int r = 0, myrank = 0, src = 0, dst = 0;
    bool valid = (e < N_EDGES);
    if (valid) {
        r = et[e]; src = ei[e]; dst = ei[N_EDGES + e];
        myrank = atomicAdd(&hloc[r], 1);
    }
    __syncthreads();
    if (t < R_REL) base[t] = hloc[t] ? atomicAdd(&cur[t], hloc[t]) : 0;
    __syncthreads();
    if (valid) {
        int p = off[r] + base[r] + myrank;
        srcs[p]   = src;
        escale[p] = finv[dst * R_REL + r];
        int q = ptr[dst] + 1 + atomicAdd(&cur2[dst], 1);
        ebyd[q] = p;
    }
}

// ---------------- root edges: slot 40, scale 1, first CSR slot of each node ----------------
__global__ void rootplace_kernel(const int* __restrict__ off, const int* __restrict__ ptr,
                                 int* __restrict__ srcs, float* __restrict__ escale,
                                 int* __restrict__ ebyd) {
    int n = blockIdx.x * blockDim.x + threadIdx.x;
    if (n >= N_NODES) return;
    int p = off[R_REL] + n;
    srcs[p]   = n;
    escale[p] = 1.0f;
    ebyd[ptr[n]] = p;
}

// ---------------- gather + bf16 convert: xb[n,:] = bf16(node_emb[node_index[n],:]) ----------------
__global__ void gather_bf16_kernel(const float* __restrict__ emb, const int* __restrict__ idx,
                                   ushort* __restrict__ xb) {
    int t = blockIdx.x * blockDim.x + threadIdx.x;   // N_NODES*16 threads
    int n = t >> 4, v = t & 15;
    const float4* s = (const float4*)(emb + (size_t)idx[n] * DIM + v * 8);
    float4 a = s[0], b = s[1];
    uint4 o;
    o.x = pk2bf(a.x, a.y); o.y = pk2bf(a.z, a.w);
    o.z = pk2bf(b.x, b.y); o.w = pk2bf(b.z, b.w);
    *(uint4*)(xb + (size_t)n * DIM + v * 8) = o;
}

// ---------------- Wf[r,k,n] = sum_b comp[r,b]*bases[b,k,n]  (f32, coalesced) ----------------
__global__ void weights_kernel(const float* __restrict__ comp,
                               const float* __restrict__ bases,
                               float* __restrict__ Wf) {
    int t = blockIdx.x * blockDim.x + threadIdx.x;   // R*DIM*DIM threads
    int col = t & (DIM - 1);
    int row = t >> 7;               // r*DIM + k
    int r = row >> 7, i = row & (DIM - 1);
    float acc = 0.f;
    #pragma unroll
    for (int b = 0; b < N_BASES; ++b)
        acc += comp[r * N_BASES + b] * bases[((size_t)b * DIM + i) * DIM + col];
    Wf[t] = acc;
}

// ---------------- transpose-convert: Wt[slot][n][k] = bf16(W[slot][k][n]); slot 40 = root ----------------
__global__ void transW_kernel(const float* __restrict__ Wf, const float* __restrict__ root,
                              ushort* __restrict__ Wt) {
    __shared__ float tile[32][33];
    int slot = blockIdx.x >> 4;
    int tb   = blockIdx.x & 15;
    int k0 = (tb >> 2) * 32, n0 = (tb & 3) * 32;
    const float* srcp = (slot < R_REL) ? (Wf + (size_t)slot * DIM * DIM) : root;
    int t = threadIdx.x;
    int tr = t >> 5, tc = t & 31;
    #pragma unroll
    for (int i = 0; i < 4; ++i)
        tile[tr + 8 * i][tc] = srcp[(size_t)(k0 + tr + 8 * i) * DIM + n0 + tc];
    __syncthreads();
    #pragma unroll
    for (int i = 0; i < 4; ++i) {
        int rr = tr + 8 * i;
        Wt[(size_t)slot * DIM * DIM + (size_t)(n0 + rr) * DIM + k0 + tc] = f2bf(tile[tc][rr]);
    }
}

// ---------------- MFMA edge GEMM v2: W staged in LDS, 128 edges/block, 32 edges/wave.
//   T[p][n] = bf16( (x[src_p] @ W[r])[n] * escale[p] ), D = Wt_slice . X^T_slice per 16x16x32.
__launch_bounds__(256)
__global__ void edge_mfma_kernel(const int* __restrict__ srcs, const float* __restrict__ escale,
                                 const int* __restrict__ off,
                                 const ushort* __restrict__ xb, const ushort* __restrict__ Wt,
                                 ushort* __restrict__ T) {
    __shared__ __align__(16) ushort Ws[DIM * DIM];   // 32 KB, 16B-slot XOR swizzled
    __shared__ int soff[R_REL + 2];
    int t = threadIdx.x;
    if (t < R_REL + 2) soff[t] = off[t];
    __syncthreads();
    int e0 = blockIdx.x * EB;
    if (e0 >= soff[R_REL + 1]) return;               // uniform exit (tail blocks)
    int r = 0;
    while (e0 >= soff[r + 1]) ++r;                   // block's W slot (0..40, uniform)

    // cooperative stage of W_r (32 KB) into LDS; 16B slot s of row -> s ^ (row&15)
    const ushort* Wr = Wt + (size_t)r * DIM * DIM;
    #pragma unroll
    for (int i = 0; i < 8; ++i) {
        int idx = t + 256 * i;                       // [0, 2048) 16B slots
        int row = idx >> 4, slot = idx & 15;
        uint4 v = *(const uint4*)(Wr + row * DIM + slot * 8);
        *(uint4*)(&Ws[row * DIM + ((slot ^ (row & 15)) * 8)]) = v;
    }
    __syncthreads();

    int wv = t >> 6;            // wave -> edges [wv*32, wv*32+32)
    int l  = t & 63;
    int lr = l & 15;            // edge col within subtile / W row within n-tile
    int lk = l >> 4;            // k sub-segment 0..3

    int er0 = e0 + wv * 32 + lr;     // subtile 0 edge
    int er1 = er0 + 16;              // subtile 1 edge
    int s0 = srcs[er0], s1 = srcs[er1];
    float esc0 = escale[er0], esc1 = escale[er1];
    const ushort* x0p = xb + (size_t)(s0 < 0 ? 0 : s0) * DIM;
    const ushort* x1p = xb + (size_t)(s1 < 0 ? 0 : s1) * DIM;

    // B-fragments (x^T) for both subtiles, all 4 k-steps, straight from global (L2-hot)
    short8 xf0[4], xf1[4];
    #pragma unroll
    for (int ks = 0; ks < 4; ++ks) {
        xf0[ks] = *(const short8*)(x0p + (ks * 4 + lk) * 8);
        xf1[ks] = *(const short8*)(x1p + (ks * 4 + lk) * 8);
    }

    f32x4 acc0[8] = {{0.f,0.f,0.f,0.f}}, acc1[8] = {{0.f,0.f,0.f,0.f}};
    #pragma unroll
    for (int mt = 0; mt < 8; ++mt) { acc0[mt] = (f32x4){0.f,0.f,0.f,0.f}; acc1[mt] = (f32x4){0.f,0.f,0.f,0.f}; }

    #pragma unroll
    for (int ks = 0; ks < 4; ++ks) {
        #pragma unroll
        for (int mt = 0; mt < 8; ++mt) {
            int row = mt * 16 + lr;
            int slot = (ks * 4 + lk) ^ lr;           // row&15 == lr
            short8 wf = *(const short8*)(&Ws[row * DIM + slot * 8]);
            acc0[mt] = __builtin_amdgcn_mfma_f32_16x16x32_bf16(wf, xf0[ks], acc0[mt], 0, 0, 0);
            acc1[mt] = __builtin_amdgcn_mfma_f32_16x16x32_bf16(wf, xf1[ks], acc1[mt], 0, 0, 0);
        }
    }

    // lane holds D[n = mt*16 + lk*4 + i][edge], i=0..3 -> 8B packed bf16 per mt
    ushort* T0 = T + (size_t)er0 * DIM;
    ushort* T1 = T + (size_t)er1 * DIM;
    #pragma unroll
    for (int mt = 0; mt < 8; ++mt) {
        uint2 p0, p1;
        p0.x = pk2bf(acc0[mt][0] * esc0, acc0[mt][1] * esc0);
        p0.y = pk2bf(acc0[mt][2] * esc0, acc0[mt][3] * esc0);
        p1.x = pk2bf(acc1[mt][0] * esc1, acc1[mt][1] * esc1);
        p1.y = pk2bf(acc1[mt][2] * esc1, acc1[mt][3] * esc1);
        *(uint2*)(T0 + mt * 16 + lk * 4) = p0;
        *(uint2*)(T1 + mt * 16 + lk * 4) = p1;
    }
}

// ---------------- aggregate: y[n,:] = bias + sum over CSR segment of T rows ----------------
template<int OUT_BF16>
__global__ void aggregate_kernel(const int* __restrict__ ptr, const int* __restrict__ ebyd,
                                 const ushort* __restrict__ T, const float* __restrict__ bias,
                                 void* __restrict__ yout) {
    int n = blockIdx.x;          // 64 threads, 2 cols each
    int t = threadIdx.x;
    int s0 = ptr[n], s1 = ptr[n + 1];
    float a0 = bias[2 * t], a1 = bias[2 * t + 1];
    for (int q = s0; q < s1; ++q) {
        int p = ebyd[q];
        uint v = *(const uint*)(T + (size_t)p * DIM + 2 * t);
        a0 += __uint_as_float(v << 16);
        a1 += __uint_as_float(v & 0xFFFF0000u);
    }
    if (OUT_BF16) {
        ((uint*)yout)[n * 64 + t] = pk2bf(a0, a1);
    } else {
        ((float2*)yout)[n * 64 + t] = make_float2(a0, a1);
    }
}

extern "C" void kernel_launch(void* const* d_in, const int* in_sizes, int n_in,
                              void* d_out, int out_size, void* d_ws, size_t ws_size,
                              hipStream_t stream) {
    const int*   node_index = (const int*)d_in[0];
    const int*   edge_index = (const int*)d_in[1];
    const int*   edge_type  = (const int*)d_in[2];
    // d_in[3] node_frequency: unused
    const float* node_emb   = (const float*)d_in[4];
    const float* comp0  = (const float*)d_in[5];
    const float* bases0 = (const float*)d_in[6];
    const float* root0  = (const float*)d_in[7];
    const float* bias0  = (const float*)d_in[8];
    const float* comp1  = (const float*)d_in[9];
    const float* bases1 = (const float*)d_in[10];
    const float* root1  = (const float*)d_in[11];
    const float* bias1  = (const float*)d_in[12];
    float* out = (float*)d_out;

    // ---- workspace layout (~113.3 MB) ----
    char* ws = (char*)d_ws;
    int*    c_cnt  = (int*)   (ws);                 //  3,200,000
    float*  finv   = (float*) (ws +  3200000);      //  3,200,000
    float*  Wf     = (float*) (ws +  6400000);      //  2,621,440 (40 slots f32)
    ushort* Wt     = (ushort*)(ws +  9021440);      //  1,343,488 (41 slots bf16 [n][k])
    ushort* x0b    = (ushort*)(ws + 10364928);      //  5,120,000
    ushort* y0b    = (ushort*)(ws + 15484928);      //  5,120,000
    int*    srcs   = (int*)   (ws + 20604928);      //  1,380,864 (P2_MAX)
    float*  escale = (float*) (ws + 21985792);      //  1,380,864
    int*    ebyd   = (int*)   (ws + 23366656);      //  1,360,000 (NE2)
    int*    meta   = (int*)   (ws + 24726656);      //  1,024: off[42]@0 h[40]@64 cur[40]@128
    int*    deg    = (int*)   (ws + 24727680);      //  80,000
    int*    cur2   = (int*)   (ws + 24807680);      //  80,000
    int*    ptr    = (int*)   (ws + 24887680);      //  80,256 (20001 ints)
    ushort* T      = (ushort*)(ws + 24967936);      // 88,375,296 (P2_MAX * 128 bf16)
    int* off = meta;
    int* h   = meta + 64;
    int* cur = meta + 128;

    // ---- build graph structures (shared by both layers) ----
    zero_kernel<<<(N_NODES * R_REL + 255) / 256, 256, 0, stream>>>(c_cnt, N_NODES * R_REL);
    zero_kernel<<<(256 + 20000 + 20000 + 255) / 256, 256, 0, stream>>>(meta, 256 + 20000 + 20000);
    count_kernel<<<(N_EDGES + 255) / 256, 256, 0, stream>>>(edge_index, edge_type, c_cnt, h, deg);
    inv_kernel<<<(N_NODES * R_REL + 255) / 256, 256, 0, stream>>>(c_cnt, finv);
    scan_kernel<<<1, 64, 0, stream>>>(h, off);
    scanptr_kernel<<<1, 256, 0, stream>>>(deg, ptr);
    fill_kernel<<<(P2_MAX + 255) / 256, 256, 0, stream>>>(srcs, escale);
    place_kernel<<<(N_EDGES + 255) / 256, 256, 0, stream>>>(edge_index, edge_type, off, cur,
                                                            finv, ptr, cur2, srcs, escale, ebyd);
    rootplace_kernel<<<(N_NODES + 255) / 256, 256, 0, stream>>>(off, ptr, srcs, escale, ebyd);
    gather_bf16_kernel<<<N_NODES * 16 / 256, 256, 0, stream>>>(node_emb, node_index, x0b);

    const int wBlocks = R_REL * DIM * DIM / 256;          // 2560
    const int tBlocks = (R_REL + 1) * 16;                 // 656
    const int eBlocks = P2_MAX / EB;                      // 2697

    // ---- layer 0 ----
    weights_kernel<<<wBlocks, 256, 0, stream>>>(comp0, bases0, Wf);
    transW_kernel<<<tBlocks, 256, 0, stream>>>(Wf, root0, Wt);
    edge_mfma_kernel<<<eBlocks, 256, 0, stream>>>(srcs, escale, off, x0b, Wt, T);
    aggregate_kernel<1><<<N_NODES, 64, 0, stream>>>(ptr, ebyd, T, bias0, y0b);

    // ---- layer 1 ----
    weights_kernel<<<wBlocks, 256, 0, stream>>>(comp1, bases1, Wf);
    transW_kernel<<<tBlocks, 256, 0, stream>>>(Wf, root1, Wt);
    edge_mfma_kernel<<<eBlocks, 256, 0, stream>>>(srcs, escale, off, y0b, Wt, T);
    aggregate_kernel<0><<<N_NODES, 64, 0, stream>>>(ptr, ebyd, T, bias1, out);
}

// Round 8
// 285.240 us; speedup vs baseline: 11.9080x; 1.0186x over previous
//
#include <hip/hip_runtime.h>

#define N_NODES  20000
#define N_EDGES  320000
#define R_REL    40
#define N_BASES  34
#define DIM      128
#define EB       128                         // edges per block (edge GEMM tile M)
#define P_PAD    (N_EDGES + R_REL * EB)      // 325120: worst-case padded relation edges
#define ROOT_PAD ((N_NODES + EB - 1) / EB * EB)  // 20096
#define P2_MAX   (P_PAD + ROOT_PAD)          // 345216 (root edges = slot 40)
#define NE2      (N_EDGES + N_NODES)         // dst-CSR entries incl. root edges

typedef unsigned int uint;
typedef unsigned short ushort;
typedef __attribute__((ext_vector_type(8))) short short8;   // 8 bf16 = 4 VGPRs
typedef __attribute__((ext_vector_type(4))) float f32x4;

__device__ __forceinline__ ushort f2bf(float f) {   // RNE fp32 -> bf16
    uint u = __float_as_uint(f);
    return (ushort)((u + 0x7FFFu + ((u >> 16) & 1u)) >> 16);
}
__device__ __forceinline__ uint pk2bf(float a, float b) {
    return (uint)f2bf(a) | ((uint)f2bf(b) << 16);
}

// ---------------- init: zero c_cnt / meta / cur2 / deg, sentinel-fill esrc ----------------
__global__ void init_kernel(int* __restrict__ c_cnt, int* __restrict__ meta_cur2_deg,
                            uint4* __restrict__ esrc) {
    int i = blockIdx.x * blockDim.x + threadIdx.x;     // 800000 threads
    if (i < N_NODES * R_REL) c_cnt[i] = 0;
    if (i < P2_MAX) esrc[i] = make_uint4((uint)-1, (uint)-1, 0u, 0u);
    if (i < 256 + 2 * N_NODES) meta_cur2_deg[i] = 0;   // meta[256] + cur2[20000] + deg[20000]
}

// ---------------- counts c[dst*R+et], relation hist h, dst degree ----------------
__global__ void count_kernel(const int* __restrict__ ei, const int* __restrict__ et,
                             int* __restrict__ c, int* __restrict__ h,
                             int* __restrict__ deg) {
    __shared__ int hloc[R_REL];
    int t = threadIdx.x;
    if (t < R_REL) hloc[t] = 0;
    __syncthreads();
    int e = blockIdx.x * blockDim.x + t;
    if (e < N_EDGES) {
        int dst = ei[N_EDGES + e];
        int r   = et[e];
        atomicAdd(&c[dst * R_REL + r], 1);
        atomicAdd(&deg[dst], 1);
        atomicAdd(&hloc[r], 1);
    }
    __syncthreads();
    if (t < R_REL && hloc[t]) atomicAdd(&h[t], hloc[t]);
}

// ---------------- finv = 1/max(c,1) ----------------
__global__ void inv_kernel(const int* __restrict__ c, float* __restrict__ finv) {
    int i = blockIdx.x * blockDim.x + threadIdx.x;
    if (i < N_NODES * R_REL) {
        int v = c[i];
        finv[i] = 1.0f / (float)(v < 1 ? 1 : v);
    }
}

// ---------------- both scans in one block: dst-CSR ptr (deg+1) and relation off ----------------
__global__ void scans_kernel(const int* __restrict__ deg, const int* __restrict__ h,
                             int* __restrict__ ptr, int* __restrict__ off) {
    __shared__ int part[256];
    const int CHn = (N_NODES + 255) / 256;     // 79
    int t = threadIdx.x;
    int s = 0;
    for (int i = 0; i < CHn; ++i) {
        int idx = t * CHn + i;
        if (idx < N_NODES) s += deg[idx] + 1;  // +1 = root slot
    }
    part[t] = s;
    __syncthreads();
    for (int d = 1; d < 256; d <<= 1) {
        int v = (t >= d) ? part[t - d] : 0;
        __syncthreads();
        part[t] += v;
        __syncthreads();
    }
    int base = (t > 0) ? part[t - 1] : 0;
    for (int i = 0; i < CHn; ++i) {
        int idx = t * CHn + i;
        if (idx < N_NODES) { ptr[idx] = base; base += deg[idx] + 1; }
    }
    if (t == 0) {
        ptr[N_NODES] = NE2;
        int acc = 0;
        off[0] = 0;
        for (int r = 0; r < R_REL; ++r) {
            acc += ((h[r] + EB - 1) / EB) * EB;
            off[r + 1] = acc;
        }
        off[R_REL + 1] = acc + ROOT_PAD;
    }
}

// ---------------- placement: real edges into relation-sorted slots + root edges (slot 40) ----
//   esrc[p] = {src, qpos (dst-CSR position), bits(escale), 0}
__global__ void place_kernel(const int* __restrict__ ei, const int* __restrict__ et,
                             const int* __restrict__ off, int* __restrict__ cur,
                             const float* __restrict__ finv,
                             const int* __restrict__ ptr, int* __restrict__ cur2,
                             uint4* __restrict__ esrc) {
    __shared__ int hloc[R_REL];
    __shared__ int base[R_REL];
    int t = threadIdx.x;
    if (t < R_REL) hloc[t] = 0;
    __syncthreads();
    int e = blockIdx.x * blockDim.x + t;       // covers N_EDGES + N_NODES
    int r = 0, myrank = 0, src = 0, dst = 0;
    bool isEdge = (e < N_EDGES);
    if (isEdge) {
        r = et[e]; src = ei[e]; dst = ei[N_EDGES + e];
        myrank = atomicAdd(&hloc[r], 1);
    }
    __syncthreads();
    if (t < R_REL) base[t] = hloc[t] ? atomicAdd(&cur[t], hloc[t]) : 0;
    __syncthreads();
    if (isEdge) {
        int p = off[r] + base[r] + myrank;
        int q = ptr[dst] + 1 + atomicAdd(&cur2[dst], 1);
        esrc[p] = make_uint4((uint)src, (uint)q,
                             __float_as_uint(finv[dst * R_REL + r]), 0u);
    } else if (e < N_EDGES + N_NODES) {
        int n = e - N_EDGES;
        esrc[off[R_REL] + n] = make_uint4((uint)n, (uint)ptr[n], 0x3f800000u, 0u);
    }
}

// ---------------- gather + bf16 convert: xb[n,:] = bf16(node_emb[node_index[n],:]) ----------------
__global__ void gather_bf16_kernel(const float* __restrict__ emb, const int* __restrict__ idx,
                                   ushort* __restrict__ xb) {
    int t = blockIdx.x * blockDim.x + threadIdx.x;   // N_NODES*16 threads
    int n = t >> 4, v = t & 15;
    const float4* s = (const float4*)(emb + (size_t)idx[n] * DIM + v * 8);
    float4 a = s[0], b = s[1];
    uint4 o;
    o.x = pk2bf(a.x, a.y); o.y = pk2bf(a.z, a.w);
    o.z = pk2bf(b.x, b.y); o.w = pk2bf(b.z, b.w);
    *(uint4*)(xb + (size_t)n * DIM + v * 8) = o;
}

// ---------------- fused basis-combine + transpose + bf16: Wt[slot][n][k]; slot 40 = root ----------------
__global__ void wtrans_kernel(const float* __restrict__ comp, const float* __restrict__ bases,
                              const float* __restrict__ root, ushort* __restrict__ Wt) {
    __shared__ float tile[32][33];
    __shared__ float scomp[N_BASES];
    int slot = blockIdx.x >> 4;                 // 0..40
    int tb   = blockIdx.x & 15;
    int k0 = (tb >> 2) * 32, n0 = (tb & 3) * 32;
    int t = threadIdx.x, tr = t >> 5, tc = t & 31;
    if (slot < R_REL) {
        if (t < N_BASES) scomp[t] = comp[slot * N_BASES + t];
        __syncthreads();
        #pragma unroll
        for (int i = 0; i < 4; ++i) {
            int kk = tr + 8 * i;
            float acc = 0.f;
            #pragma unroll
            for (int b = 0; b < N_BASES; ++b)
                acc += scomp[b] * bases[((size_t)b * DIM + k0 + kk) * DIM + n0 + tc];
            tile[kk][tc] = acc;
        }
    } else {
        #pragma unroll
        for (int i = 0; i < 4; ++i) {
            int kk = tr + 8 * i;
            tile[kk][tc] = root[(size_t)(k0 + kk) * DIM + n0 + tc];
        }
    }
    __syncthreads();
    #pragma unroll
    for (int i = 0; i < 4; ++i) {
        int rr = tr + 8 * i;
        Wt[(size_t)slot * DIM * DIM + (size_t)(n0 + rr) * DIM + k0 + tc] = f2bf(tile[tc][rr]);
    }
}

// ---------------- MFMA edge GEMM: W in LDS, 128 edges/block, 32/wave; writes T in dst-CSR order.
__launch_bounds__(256)
__global__ void edge_mfma_kernel(const uint4* __restrict__ esrc, const int* __restrict__ off,
                                 const ushort* __restrict__ xb, const ushort* __restrict__ Wt,
                                 ushort* __restrict__ T) {
    __shared__ __align__(16) ushort Ws[DIM * DIM];   // 32 KB, 16B-slot XOR swizzled
    __shared__ int soff[R_REL + 2];
    int t = threadIdx.x;
    if (t < R_REL + 2) soff[t] = off[t];
    __syncthreads();
    int e0 = blockIdx.x * EB;
    if (e0 >= soff[R_REL + 1]) return;               // uniform exit (tail blocks)
    int r = 0;
    while (e0 >= soff[r + 1]) ++r;                   // block's W slot (0..40, uniform)

    // cooperative stage of W_r (32 KB) into LDS; 16B slot s of row -> s ^ (row&15)
    const ushort* Wr = Wt + (size_t)r * DIM * DIM;
    #pragma unroll
    for (int i = 0; i < 8; ++i) {
        int idx = t + 256 * i;                       // [0, 2048) 16B slots
        int row = idx >> 4, slot = idx & 15;
        uint4 v = *(const uint4*)(Wr + row * DIM + slot * 8);
        *(uint4*)(&Ws[row * DIM + ((slot ^ (row & 15)) * 8)]) = v;
    }
    __syncthreads();

    int wv = t >> 6;            // wave -> edges [wv*32, wv*32+32)
    int l  = t & 63;
    int lr = l & 15;            // edge col within subtile / W row within n-tile
    int lk = l >> 4;            // k sub-segment 0..3

    int er0 = e0 + wv * 32 + lr;     // subtile 0 edge
    int er1 = er0 + 16;              // subtile 1 edge
    uint4 es0 = esrc[er0], es1 = esrc[er1];
    int s0 = (int)es0.x, q0 = (int)es0.y;
    int s1 = (int)es1.x, q1 = (int)es1.y;
    float esc0 = __uint_as_float(es0.z), esc1 = __uint_as_float(es1.z);
    const ushort* x0p = xb + (size_t)(s0 < 0 ? 0 : s0) * DIM;
    const ushort* x1p = xb + (size_t)(s1 < 0 ? 0 : s1) * DIM;

    // B-fragments (x^T) for both subtiles, all 4 k-steps (x is L2-resident, 5 MB)
    short8 xf0[4], xf1[4];
    #pragma unroll
    for (int ks = 0; ks < 4; ++ks) {
        xf0[ks] = *(const short8*)(x0p + (ks * 4 + lk) * 8);
        xf1[ks] = *(const short8*)(x1p + (ks * 4 + lk) * 8);
    }

    f32x4 acc0[8], acc1[8];
    #pragma unroll
    for (int mt = 0; mt < 8; ++mt) { acc0[mt] = (f32x4){0.f,0.f,0.f,0.f}; acc1[mt] = (f32x4){0.f,0.f,0.f,0.f}; }

    #pragma unroll
    for (int ks = 0; ks < 4; ++ks) {
        #pragma unroll
        for (int mt = 0; mt < 8; ++mt) {
            int row = mt * 16 + lr;
            int slot = (ks * 4 + lk) ^ lr;           // row&15 == lr
            short8 wf = *(const short8*)(&Ws[row * DIM + slot * 8]);
            acc0[mt] = __builtin_amdgcn_mfma_f32_16x16x32_bf16(wf, xf0[ks], acc0[mt], 0, 0, 0);
            acc1[mt] = __builtin_amdgcn_mfma_f32_16x16x32_bf16(wf, xf1[ks], acc1[mt], 0, 0, 0);
        }
    }

    // lane holds D[n = mt*16 + lk*4 + i][edge]; write to dst-CSR row q (skip padding q<0)
    ushort* T0 = T + (size_t)q0 * DIM;
    ushort* T1 = T + (size_t)q1 * DIM;
    #pragma unroll
    for (int mt = 0; mt < 8; ++mt) {
        if (q0 >= 0) {
            uint2 p0;
            p0.x = pk2bf(acc0[mt][0] * esc0, acc0[mt][1] * esc0);
            p0.y = pk2bf(acc0[mt][2] * esc0, acc0[mt][3] * esc0);
            *(uint2*)(T0 + mt * 16 + lk * 4) = p0;
        }
        if (q1 >= 0) {
            uint2 p1;
            p1.x = pk2bf(acc1[mt][0] * esc1, acc1[mt][1] * esc1);
            p1.y = pk2bf(acc1[mt][2] * esc1, acc1[mt][3] * esc1);
            *(uint2*)(T1 + mt * 16 + lk * 4) = p1;
        }
    }
}

// ---------------- aggregate: y[n,:] = bias + sum_{q in [ptr[n],ptr[n+1])} T[q,:]  (sequential!) ----
template<int OUT_BF16>
__global__ void aggregate_kernel(const int* __restrict__ ptr, const ushort* __restrict__ T,
                                 const float* __restrict__ bias, void* __restrict__ yout) {
    int n = blockIdx.x;          // 64 threads, 2 cols each
    int t = threadIdx.x;
    int s0 = ptr[n], s1 = ptr[n + 1];
    float a0 = bias[2 * t], a1 = bias[2 * t + 1];
    for (int q = s0; q < s1; ++q) {
        uint v = *(const uint*)(T + (size_t)q * DIM + 2 * t);
        a0 += __uint_as_float(v << 16);
        a1 += __uint_as_float(v & 0xFFFF0000u);
    }
    if (OUT_BF16) {
        ((uint*)yout)[n * 64 + t] = pk2bf(a0, a1);
    } else {
        ((float2*)yout)[n * 64 + t] = make_float2(a0, a1);
    }
}

extern "C" void kernel_launch(void* const* d_in, const int* in_sizes, int n_in,
                              void* d_out, int out_size, void* d_ws, size_t ws_size,
                              hipStream_t stream) {
    const int*   node_index = (const int*)d_in[0];
    const int*   edge_index = (const int*)d_in[1];
    const int*   edge_type  = (const int*)d_in[2];
    // d_in[3] node_frequency: unused
    const float* node_emb   = (const float*)d_in[4];
    const float* comp0  = (const float*)d_in[5];
    const float* bases0 = (const float*)d_in[6];
    const float* root0  = (const float*)d_in[7];
    const float* bias0  = (const float*)d_in[8];
    const float* comp1  = (const float*)d_in[9];
    const float* bases1 = (const float*)d_in[10];
    const float* root1  = (const float*)d_in[11];
    const float* bias1  = (const float*)d_in[12];
    float* out = (float*)d_out;

    // ---- workspace layout (~111 MB) ----
    char* ws = (char*)d_ws;
    int*    c_cnt  = (int*)   (ws);                 //  3,200,000
    float*  finv   = (float*) (ws +  3200000);      //  3,200,000
    ushort* Wt     = (ushort*)(ws +  6400000);      //  1,343,488 (41 slots bf16 [n][k])
    ushort* x0b    = (ushort*)(ws +  7743488);      //  5,120,000
    ushort* y0b    = (ushort*)(ws + 12863488);      //  5,120,000
    uint4*  esrc   = (uint4*) (ws + 17983488);      //  5,523,456 (P2_MAX * 16B)
    int*    meta   = (int*)   (ws + 23506944);      //  1,024: off[42]@0 h[40]@64 cur[40]@128
    int*    cur2   = (int*)   (ws + 23507968);      //  80,000 (contiguous after meta)
    int*    deg    = (int*)   (ws + 23587968);      //  80,000 (contiguous after cur2)
    int*    ptr    = (int*)   (ws + 23667968);      //  80,256 (20001 ints)
    ushort* T      = (ushort*)(ws + 23748480);      // 87,040,000 (NE2 * 128 bf16)
    int* off = meta;
    int* h   = meta + 64;
    int* cur = meta + 128;

    // ---- build graph structures (shared by both layers) ----
    init_kernel<<<(N_NODES * R_REL + 255) / 256, 256, 0, stream>>>(c_cnt, meta, esrc);
    count_kernel<<<(N_EDGES + 255) / 256, 256, 0, stream>>>(edge_index, edge_type, c_cnt, h, deg);
    inv_kernel<<<(N_NODES * R_REL + 255) / 256, 256, 0, stream>>>(c_cnt, finv);
    scans_kernel<<<1, 256, 0, stream>>>(deg, h, ptr, off);
    place_kernel<<<(N_EDGES + N_NODES + 255) / 256, 256, 0, stream>>>(
        edge_index, edge_type, off, cur, finv, ptr, cur2, esrc);
    gather_bf16_kernel<<<N_NODES * 16 / 256, 256, 0, stream>>>(node_emb, node_index, x0b);

    const int wtBlocks = (R_REL + 1) * 16;                // 656
    const int eBlocks  = P2_MAX / EB;                     // 2697

    // ---- layer 0 ----
    wtrans_kernel<<<wtBlocks, 256, 0, stream>>>(comp0, bases0, root0, Wt);
    edge_mfma_kernel<<<eBlocks, 256, 0, stream>>>(esrc, off, x0b, Wt, T);
    aggregate_kernel<1><<<N_NODES, 64, 0, stream>>>(ptr, T, bias0, y0b);

    // ---- layer 1 ----
    wtrans_kernel<<<wtBlocks, 256, 0, stream>>>(comp1, bases1, root1, Wt);
    edge_mfma_kernel<<<eBlocks, 256, 0, stream>>>(esrc, off, y0b, Wt, T);
    aggregate_kernel<0><<<N_NODES, 64, 0, stream>>>(ptr, T, bias1, out);
}

// Round 9
// 284.492 us; speedup vs baseline: 11.9393x; 1.0026x over previous
//
#include <hip/hip_runtime.h>

#define N_NODES  20000
#define N_EDGES  320000
#define R_REL    40
#define N_BASES  34
#define DIM      128
#define EB       128                         // edges per chunk (edge GEMM tile M)
#define P_PAD    (N_EDGES + R_REL * EB)      // 325120: worst-case padded relation edges
#define ROOT_PAD ((N_NODES + EB - 1) / EB * EB)  // 20096
#define P2_MAX   (P_PAD + ROOT_PAD)          // 345216 (root edges = slot 40)
#define NE2      (N_EDGES + N_NODES)         // dst-CSR entries incl. root edges
#define NSLOT    (R_REL + 1)                 // 41 weight slots

typedef unsigned int uint;
typedef unsigned short ushort;
typedef __attribute__((ext_vector_type(8))) short short8;   // 8 bf16 = 4 VGPRs
typedef __attribute__((ext_vector_type(4))) float f32x4;

__device__ __forceinline__ ushort f2bf(float f) {   // RNE fp32 -> bf16
    uint u = __float_as_uint(f);
    return (ushort)((u + 0x7FFFu + ((u >> 16) & 1u)) >> 16);
}
__device__ __forceinline__ uint pk2bf(float a, float b) {
    return (uint)f2bf(a) | ((uint)f2bf(b) << 16);
}

// ---------------- init: zero c_cnt / meta / cur2 / deg, sentinel-fill esrc ----------------
__global__ void init_kernel(int* __restrict__ c_cnt, int* __restrict__ meta_cur2_deg,
                            uint4* __restrict__ esrc) {
    int i = blockIdx.x * blockDim.x + threadIdx.x;     // 800000 threads
    if (i < N_NODES * R_REL) c_cnt[i] = 0;
    if (i < P2_MAX) esrc[i] = make_uint4((uint)-1, (uint)-1, 0u, 0u);
    if (i < 256 + 2 * N_NODES) meta_cur2_deg[i] = 0;   // meta[256] + cur2[20000] + deg[20000]
}

// ---------------- counts c[dst*R+et], relation hist h, dst degree ----------------
__global__ void count_kernel(const int* __restrict__ ei, const int* __restrict__ et,
                             int* __restrict__ c, int* __restrict__ h,
                             int* __restrict__ deg) {
    __shared__ int hloc[R_REL];
    int t = threadIdx.x;
    if (t < R_REL) hloc[t] = 0;
    __syncthreads();
    int e = blockIdx.x * blockDim.x + t;
    if (e < N_EDGES) {
        int dst = ei[N_EDGES + e];
        int r   = et[e];
        atomicAdd(&c[dst * R_REL + r], 1);
        atomicAdd(&deg[dst], 1);
        atomicAdd(&hloc[r], 1);
    }
    __syncthreads();
    if (t < R_REL && hloc[t]) atomicAdd(&h[t], hloc[t]);
}

// ---------------- both scans in one 1024-thread block: dst-CSR ptr (deg+1), relation off ----
__global__ void scans_kernel(const int* __restrict__ deg, const int* __restrict__ h,
                             int* __restrict__ ptr, int* __restrict__ off) {
    __shared__ int part[1024];
    const int CHn = (N_NODES + 1023) / 1024;   // 20
    int t = threadIdx.x;
    int s = 0;
    for (int i = 0; i < CHn; ++i) {
        int idx = t * CHn + i;
        if (idx < N_NODES) s += deg[idx] + 1;  // +1 = root slot
    }
    part[t] = s;
    __syncthreads();
    for (int d = 1; d < 1024; d <<= 1) {
        int v = (t >= d) ? part[t - d] : 0;
        __syncthreads();
        part[t] += v;
        __syncthreads();
    }
    int base = (t > 0) ? part[t - 1] : 0;
    for (int i = 0; i < CHn; ++i) {
        int idx = t * CHn + i;
        if (idx < N_NODES) { ptr[idx] = base; base += deg[idx] + 1; }
    }
    if (t == 0) {
        ptr[N_NODES] = NE2;
        int acc = 0;
        off[0] = 0;
        for (int r = 0; r < R_REL; ++r) {
            acc += ((h[r] + EB - 1) / EB) * EB;
            off[r + 1] = acc;
        }
        off[R_REL + 1] = acc + ROOT_PAD;
    }
}

// ---------------- placement (finv computed inline from c_cnt): real + root edges ----------
//   esrc[p] = {src, qpos (dst-CSR position), bits(escale), 0}
__global__ void place_kernel(const int* __restrict__ ei, const int* __restrict__ et,
                             const int* __restrict__ off, int* __restrict__ cur,
                             const int* __restrict__ c_cnt,
                             const int* __restrict__ ptr, int* __restrict__ cur2,
                             uint4* __restrict__ esrc) {
    __shared__ int hloc[R_REL];
    __shared__ int base[R_REL];
    int t = threadIdx.x;
    if (t < R_REL) hloc[t] = 0;
    __syncthreads();
    int e = blockIdx.x * blockDim.x + t;       // covers N_EDGES + N_NODES
    int r = 0, myrank = 0, src = 0, dst = 0;
    bool isEdge = (e < N_EDGES);
    if (isEdge) {
        r = et[e]; src = ei[e]; dst = ei[N_EDGES + e];
        myrank = atomicAdd(&hloc[r], 1);
    }
    __syncthreads();
    if (t < R_REL) base[t] = hloc[t] ? atomicAdd(&cur[t], hloc[t]) : 0;
    __syncthreads();
    if (isEdge) {
        int p = off[r] + base[r] + myrank;
        int q = ptr[dst] + 1 + atomicAdd(&cur2[dst], 1);
        int cnt = c_cnt[dst * R_REL + r];
        float esc = 1.0f / (float)(cnt < 1 ? 1 : cnt);
        esrc[p] = make_uint4((uint)src, (uint)q, __float_as_uint(esc), 0u);
    } else if (e < N_EDGES + N_NODES) {
        int n = e - N_EDGES;
        esrc[off[R_REL] + n] = make_uint4((uint)n, (uint)ptr[n], 0x3f800000u, 0u);
    }
}

// ---------------- gather + bf16 convert: xb[n,:] = bf16(node_emb[node_index[n],:]) ----------------
__global__ void gather_bf16_kernel(const float* __restrict__ emb, const int* __restrict__ idx,
                                   ushort* __restrict__ xb) {
    int t = blockIdx.x * blockDim.x + threadIdx.x;   // N_NODES*16 threads
    int n = t >> 4, v = t & 15;
    const float4* s = (const float4*)(emb + (size_t)idx[n] * DIM + v * 8);
    float4 a = s[0], b = s[1];
    uint4 o;
    o.x = pk2bf(a.x, a.y); o.y = pk2bf(a.z, a.w);
    o.z = pk2bf(b.x, b.y); o.w = pk2bf(b.z, b.w);
    *(uint4*)(xb + (size_t)n * DIM + v * 8) = o;
}

// ---------------- fused basis-combine + transpose + bf16 for BOTH layers in one dispatch ----
//   Wt[layer][slot][n][k]; slot 40 = root.
__global__ void wtrans_kernel(const float* __restrict__ comp0, const float* __restrict__ bases0,
                              const float* __restrict__ root0,
                              const float* __restrict__ comp1, const float* __restrict__ bases1,
                              const float* __restrict__ root1,
                              ushort* __restrict__ Wt) {
    __shared__ float tile[32][33];
    __shared__ float scomp[N_BASES];
    int b = blockIdx.x;                         // 0..2*656-1
    int layer = (b >= NSLOT * 16) ? 1 : 0;
    int bb = b - layer * NSLOT * 16;
    const float* comp  = layer ? comp1  : comp0;
    const float* bases = layer ? bases1 : bases0;
    const float* root  = layer ? root1  : root0;
    int slot = bb >> 4;                         // 0..40
    int tb   = bb & 15;
    int k0 = (tb >> 2) * 32, n0 = (tb & 3) * 32;
    int t = threadIdx.x, tr = t >> 5, tc = t & 31;
    if (slot < R_REL) {
        if (t < N_BASES) scomp[t] = comp[slot * N_BASES + t];
        __syncthreads();
        #pragma unroll
        for (int i = 0; i < 4; ++i) {
            int kk = tr + 8 * i;
            float acc = 0.f;
            #pragma unroll
            for (int bs = 0; bs < N_BASES; ++bs)
                acc += scomp[bs] * bases[((size_t)bs * DIM + k0 + kk) * DIM + n0 + tc];
            tile[kk][tc] = acc;
        }
    } else {
        #pragma unroll
        for (int i = 0; i < 4; ++i) {
            int kk = tr + 8 * i;
            tile[kk][tc] = root[(size_t)(k0 + kk) * DIM + n0 + tc];
        }
    }
    __syncthreads();
    size_t obase = ((size_t)layer * NSLOT + slot) * DIM * DIM;
    #pragma unroll
    for (int i = 0; i < 4; ++i) {
        int rr = tr + 8 * i;
        Wt[obase + (size_t)(n0 + rr) * DIM + k0 + tc] = f2bf(tile[tc][rr]);
    }
}

// ---------------- persistent-relation MFMA edge GEMM: W staged ONCE per block,
//   block (r, sub) chunk-strides over relation r's 128-edge chunks; writes T in dst-CSR order.
#define SUBS 32
__launch_bounds__(256)
__global__ void edge_mfma_kernel(const uint4* __restrict__ esrc, const int* __restrict__ off,
                                 const ushort* __restrict__ xb, const ushort* __restrict__ Wt,
                                 ushort* __restrict__ T) {
    __shared__ __align__(16) ushort Ws[DIM * DIM];   // 32 KB, 16B-slot XOR swizzled
    int t = threadIdx.x;
    int r   = blockIdx.x >> 5;                       // 0..40 (uniform)
    int sub = blockIdx.x & (SUBS - 1);
    int s_lo = off[r], s_hi = off[r + 1];            // uniform scalar loads; multiples of 128

    // cooperative stage of W_r (32 KB) into LDS; 16B slot s of row -> s ^ (row&15)
    const ushort* Wr = Wt + (size_t)r * DIM * DIM;
    #pragma unroll
    for (int i = 0; i < 8; ++i) {
        int idx = t + 256 * i;                       // [0, 2048) 16B slots
        int row = idx >> 4, slot = idx & 15;
        uint4 v = *(const uint4*)(Wr + row * DIM + slot * 8);
        *(uint4*)(&Ws[row * DIM + ((slot ^ (row & 15)) * 8)]) = v;
    }
    __syncthreads();

    int wv = t >> 6;            // wave -> edges [wv*32, wv*32+32) within chunk
    int l  = t & 63;
    int lr = l & 15;            // edge col within subtile / W row within n-tile
    int lk = l >> 4;            // k sub-segment 0..3

    int nch = (s_hi - s_lo) >> 7;                    // chunks of this relation
    for (int c = sub; c < nch; c += SUBS) {
        int e0 = s_lo + (c << 7);
        int er0 = e0 + wv * 32 + lr;     // subtile 0 edge
        int er1 = er0 + 16;              // subtile 1 edge
        uint4 es0 = esrc[er0], es1 = esrc[er1];
        int s0 = (int)es0.x, q0 = (int)es0.y;
        int s1 = (int)es1.x, q1 = (int)es1.y;
        float esc0 = __uint_as_float(es0.z), esc1 = __uint_as_float(es1.z);
        const ushort* x0p = xb + (size_t)(s0 < 0 ? 0 : s0) * DIM;
        const ushort* x1p = xb + (size_t)(s1 < 0 ? 0 : s1) * DIM;

        // B-fragments (x^T) for both subtiles, all 4 k-steps (x is L2-resident, 5 MB)
        short8 xf0[4], xf1[4];
        #pragma unroll
        for (int ks = 0; ks < 4; ++ks) {
            xf0[ks] = *(const short8*)(x0p + (ks * 4 + lk) * 8);
            xf1[ks] = *(const short8*)(x1p + (ks * 4 + lk) * 8);
        }

        f32x4 acc0[8], acc1[8];
        #pragma unroll
        for (int mt = 0; mt < 8; ++mt) {
            acc0[mt] = (f32x4){0.f, 0.f, 0.f, 0.f};
            acc1[mt] = (f32x4){0.f, 0.f, 0.f, 0.f};
        }

        #pragma unroll
        for (int ks = 0; ks < 4; ++ks) {
            #pragma unroll
            for (int mt = 0; mt < 8; ++mt) {
                int row = mt * 16 + lr;
                int slot = (ks * 4 + lk) ^ lr;       // row&15 == lr
                short8 wf = *(const short8*)(&Ws[row * DIM + slot * 8]);
                acc0[mt] = __builtin_amdgcn_mfma_f32_16x16x32_bf16(wf, xf0[ks], acc0[mt], 0, 0, 0);
                acc1[mt] = __builtin_amdgcn_mfma_f32_16x16x32_bf16(wf, xf1[ks], acc1[mt], 0, 0, 0);
            }
        }

        // lane holds D[n = mt*16 + lk*4 + i][edge]; write to dst-CSR row q (skip padding q<0)
        ushort* T0 = T + (size_t)q0 * DIM;
        ushort* T1 = T + (size_t)q1 * DIM;
        #pragma unroll
        for (int mt = 0; mt < 8; ++mt) {
            if (q0 >= 0) {
                uint2 p0;
                p0.x = pk2bf(acc0[mt][0] * esc0, acc0[mt][1] * esc0);
                p0.y = pk2bf(acc0[mt][2] * esc0, acc0[mt][3] * esc0);
                *(uint2*)(T0 + mt * 16 + lk * 4) = p0;
            }
            if (q1 >= 0) {
                uint2 p1;
                p1.x = pk2bf(acc1[mt][0] * esc1, acc1[mt][1] * esc1);
                p1.y = pk2bf(acc1[mt][2] * esc1, acc1[mt][3] * esc1);
                *(uint2*)(T1 + mt * 16 + lk * 4) = p1;
            }
        }
    }
}

// ---------------- aggregate: y[n,:] = bias + sum_{q in [ptr[n],ptr[n+1])} T[q,:] (sequential);
//   2 nodes per 128-thread block.
template<int OUT_BF16>
__global__ void aggregate_kernel(const int* __restrict__ ptr, const ushort* __restrict__ T,
                                 const float* __restrict__ bias, void* __restrict__ yout) {
    int t = threadIdx.x;
    int n = blockIdx.x * 2 + (t >> 6);   // N_NODES is even
    int tt = t & 63;                     // 64 threads per node, 2 cols each
    int s0 = ptr[n], s1 = ptr[n + 1];
    float a0 = bias[2 * tt], a1 = bias[2 * tt + 1];
    for (int q = s0; q < s1; ++q) {
        uint v = *(const uint*)(T + (size_t)q * DIM + 2 * tt);
        a0 += __uint_as_float(v << 16);
        a1 += __uint_as_float(v & 0xFFFF0000u);
    }
    if (OUT_BF16) {
        ((uint*)yout)[n * 64 + tt] = pk2bf(a0, a1);
    } else {
        ((float2*)yout)[n * 64 + tt] = make_float2(a0, a1);
    }
}

extern "C" void kernel_launch(void* const* d_in, const int* in_sizes, int n_in,
                              void* d_out, int out_size, void* d_ws, size_t ws_size,
                              hipStream_t stream) {
    const int*   node_index = (const int*)d_in[0];
    const int*   edge_index = (const int*)d_in[1];
    const int*   edge_type  = (const int*)d_in[2];
    // d_in[3] node_frequency: unused
    const float* node_emb   = (const float*)d_in[4];
    const float* comp0  = (const float*)d_in[5];
    const float* bases0 = (const float*)d_in[6];
    const float* root0  = (const float*)d_in[7];
    const float* bias0  = (const float*)d_in[8];
    const float* comp1  = (const float*)d_in[9];
    const float* bases1 = (const float*)d_in[10];
    const float* root1  = (const float*)d_in[11];
    const float* bias1  = (const float*)d_in[12];
    float* out = (float*)d_out;

    // ---- workspace layout (~109 MB) ----
    char* ws = (char*)d_ws;
    int*    c_cnt  = (int*)   (ws);                 //  3,200,000
    ushort* Wt     = (ushort*)(ws +  3200000);      //  2,686,976 (2 layers x 41 slots bf16 [n][k])
    ushort* x0b    = (ushort*)(ws +  5886976);      //  5,120,000
    ushort* y0b    = (ushort*)(ws + 11006976);      //  5,120,000
    uint4*  esrc   = (uint4*) (ws + 16126976);      //  5,523,456 (P2_MAX * 16B)
    int*    meta   = (int*)   (ws + 21650432);      //  1,024: off[42]@0 h[40]@64 cur[40]@128
    int*    cur2   = (int*)   (ws + 21651456);      //  80,000 (contiguous after meta)
    int*    deg    = (int*)   (ws + 21731456);      //  80,000 (contiguous after cur2)
    int*    ptr    = (int*)   (ws + 21811456);      //  80,256 (20001 ints)
    ushort* T      = (ushort*)(ws + 21891712);      // 87,040,000 (NE2 * 128 bf16)
    int* off = meta;
    int* h   = meta + 64;
    int* cur = meta + 128;

    // ---- build graph structures (shared by both layers) ----
    init_kernel<<<(N_NODES * R_REL + 255) / 256, 256, 0, stream>>>(c_cnt, meta, esrc);
    count_kernel<<<(N_EDGES + 255) / 256, 256, 0, stream>>>(edge_index, edge_type, c_cnt, h, deg);
    scans_kernel<<<1, 1024, 0, stream>>>(deg, h, ptr, off);
    place_kernel<<<(N_EDGES + N_NODES + 255) / 256, 256, 0, stream>>>(
        edge_index, edge_type, off, cur, c_cnt, ptr, cur2, esrc);
    gather_bf16_kernel<<<N_NODES * 16 / 256, 256, 0, stream>>>(node_emb, node_index, x0b);
    wtrans_kernel<<<2 * NSLOT * 16, 256, 0, stream>>>(comp0, bases0, root0,
                                                      comp1, bases1, root1, Wt);

    const int eBlocks = NSLOT * SUBS;                     // 1312 persistent-relation blocks

    // ---- layer 0 ----
    edge_mfma_kernel<<<eBlocks, 256, 0, stream>>>(esrc, off, x0b, Wt, T);
    aggregate_kernel<1><<<N_NODES / 2, 128, 0, stream>>>(ptr, T, bias0, y0b);

    // ---- layer 1 ----
    edge_mfma_kernel<<<eBlocks, 256, 0, stream>>>(esrc, off, y0b,
                                                  Wt + (size_t)NSLOT * DIM * DIM, T);
    aggregate_kernel<0><<<N_NODES / 2, 128, 0, stream>>>(ptr, T, bias1, out);
}

// Round 10
// 274.003 us; speedup vs baseline: 12.3963x; 1.0383x over previous
//
#include <hip/hip_runtime.h>

#define N_NODES  20000
#define N_EDGES  320000
#define R_REL    40
#define N_BASES  34
#define DIM      128
#define EB       128                         // edges per block (edge GEMM tile M)
#define P_PAD    (N_EDGES + R_REL * EB)      // 325120: worst-case padded relation edges
#define ROOT_PAD ((N_NODES + EB - 1) / EB * EB)  // 20096
#define P2_MAX   (P_PAD + ROOT_PAD)          // 345216 (root edges = slot 40)
#define NE2      (N_EDGES + N_NODES)         // dst-CSR entries incl. root edges
#define NSLOT    (R_REL + 1)                 // 41 weight slots

typedef unsigned int uint;
typedef unsigned short ushort;
typedef __attribute__((ext_vector_type(8))) short short8;   // 8 bf16 = 4 VGPRs
typedef __attribute__((ext_vector_type(4))) float f32x4;

__device__ __forceinline__ ushort f2bf(float f) {   // RNE fp32 -> bf16
    uint u = __float_as_uint(f);
    return (ushort)((u + 0x7FFFu + ((u >> 16) & 1u)) >> 16);
}
__device__ __forceinline__ uint pk2bf(float a, float b) {
    return (uint)f2bf(a) | ((uint)f2bf(b) << 16);
}

// ---------------- init: zero c_cnt / meta / cur2 / deg, sentinel-fill esrc ----------------
__global__ void init_kernel(int* __restrict__ c_cnt, int* __restrict__ meta_cur2_deg,
                            uint4* __restrict__ esrc) {
    int i = blockIdx.x * blockDim.x + threadIdx.x;     // 800000 threads
    if (i < N_NODES * R_REL) c_cnt[i] = 0;
    if (i < P2_MAX) esrc[i] = make_uint4((uint)-1, (uint)-1, 0u, 0u);
    if (i < 256 + 2 * N_NODES) meta_cur2_deg[i] = 0;   // meta[256] + cur2[20000] + deg[20000]
}

// ---------------- counts c[dst*R+et], relation hist h, dst degree ----------------
__global__ void count_kernel(const int* __restrict__ ei, const int* __restrict__ et,
                             int* __restrict__ c, int* __restrict__ h,
                             int* __restrict__ deg) {
    __shared__ int hloc[R_REL];
    int t = threadIdx.x;
    if (t < R_REL) hloc[t] = 0;
    __syncthreads();
    int e = blockIdx.x * blockDim.x + t;
    if (e < N_EDGES) {
        int dst = ei[N_EDGES + e];
        int r   = et[e];
        atomicAdd(&c[dst * R_REL + r], 1);
        atomicAdd(&deg[dst], 1);
        atomicAdd(&hloc[r], 1);
    }
    __syncthreads();
    if (t < R_REL && hloc[t]) atomicAdd(&h[t], hloc[t]);
}

// ---------------- both scans in one 1024-thread block: dst-CSR ptr (deg+1), relation off ----
__global__ void scans_kernel(const int* __restrict__ deg, const int* __restrict__ h,
                             int* __restrict__ ptr, int* __restrict__ off) {
    __shared__ int part[1024];
    const int CHn = (N_NODES + 1023) / 1024;   // 20
    int t = threadIdx.x;
    int s = 0;
    for (int i = 0; i < CHn; ++i) {
        int idx = t * CHn + i;
        if (idx < N_NODES) s += deg[idx] + 1;  // +1 = root slot
    }
    part[t] = s;
    __syncthreads();
    for (int d = 1; d < 1024; d <<= 1) {
        int v = (t >= d) ? part[t - d] : 0;
        __syncthreads();
        part[t] += v;
        __syncthreads();
    }
    int base = (t > 0) ? part[t - 1] : 0;
    for (int i = 0; i < CHn; ++i) {
        int idx = t * CHn + i;
        if (idx < N_NODES) { ptr[idx] = base; base += deg[idx] + 1; }
    }
    if (t == 0) {
        ptr[N_NODES] = NE2;
        int acc = 0;
        off[0] = 0;
        for (int r = 0; r < R_REL; ++r) {
            acc += ((h[r] + EB - 1) / EB) * EB;
            off[r + 1] = acc;
        }
        off[R_REL + 1] = acc + ROOT_PAD;
    }
}

// ---------------- placement (finv computed inline from c_cnt): real + root edges ----------
//   esrc[p] = {src, qpos (dst-CSR position), bits(escale), 0}
__global__ void place_kernel(const int* __restrict__ ei, const int* __restrict__ et,
                             const int* __restrict__ off, int* __restrict__ cur,
                             const int* __restrict__ c_cnt,
                             const int* __restrict__ ptr, int* __restrict__ cur2,
                             uint4* __restrict__ esrc) {
    __shared__ int hloc[R_REL];
    __shared__ int base[R_REL];
    int t = threadIdx.x;
    if (t < R_REL) hloc[t] = 0;
    __syncthreads();
    int e = blockIdx.x * blockDim.x + t;       // covers N_EDGES + N_NODES
    int r = 0, myrank = 0, src = 0, dst = 0;
    bool isEdge = (e < N_EDGES);
    if (isEdge) {
        r = et[e]; src = ei[e]; dst = ei[N_EDGES + e];
        myrank = atomicAdd(&hloc[r], 1);
    }
    __syncthreads();
    if (t < R_REL) base[t] = hloc[t] ? atomicAdd(&cur[t], hloc[t]) : 0;
    __syncthreads();
    if (isEdge) {
        int p = off[r] + base[r] + myrank;
        int q = ptr[dst] + 1 + atomicAdd(&cur2[dst], 1);
        int cnt = c_cnt[dst * R_REL + r];
        float esc = 1.0f / (float)(cnt < 1 ? 1 : cnt);
        esrc[p] = make_uint4((uint)src, (uint)q, __float_as_uint(esc), 0u);
    } else if (e < N_EDGES + N_NODES) {
        int n = e - N_EDGES;
        esrc[off[R_REL] + n] = make_uint4((uint)n, (uint)ptr[n], 0x3f800000u, 0u);
    }
}

// ---------------- gather + bf16 convert: xb[n,:] = bf16(node_emb[node_index[n],:]) ----------------
__global__ void gather_bf16_kernel(const float* __restrict__ emb, const int* __restrict__ idx,
                                   ushort* __restrict__ xb) {
    int t = blockIdx.x * blockDim.x + threadIdx.x;   // N_NODES*16 threads
    int n = t >> 4, v = t & 15;
    const float4* s = (const float4*)(emb + (size_t)idx[n] * DIM + v * 8);
    float4 a = s[0], b = s[1];
    uint4 o;
    o.x = pk2bf(a.x, a.y); o.y = pk2bf(a.z, a.w);
    o.z = pk2bf(b.x, b.y); o.w = pk2bf(b.z, b.w);
    *(uint4*)(xb + (size_t)n * DIM + v * 8) = o;
}

// ---------------- fused basis-combine + transpose + bf16 for BOTH layers in one dispatch ----
//   Wt[layer][slot][n][k]; slot 40 = root.
__global__ void wtrans_kernel(const float* __restrict__ comp0, const float* __restrict__ bases0,
                              const float* __restrict__ root0,
                              const float* __restrict__ comp1, const float* __restrict__ bases1,
                              const float* __restrict__ root1,
                              ushort* __restrict__ Wt) {
    __shared__ float tile[32][33];
    __shared__ float scomp[N_BASES];
    int b = blockIdx.x;                         // 0..2*656-1
    int layer = (b >= NSLOT * 16) ? 1 : 0;
    int bb = b - layer * NSLOT * 16;
    const float* comp  = layer ? comp1  : comp0;
    const float* bases = layer ? bases1 : bases0;
    const float* root  = layer ? root1  : root0;
    int slot = bb >> 4;                         // 0..40
    int tb   = bb & 15;
    int k0 = (tb >> 2) * 32, n0 = (tb & 3) * 32;
    int t = threadIdx.x, tr = t >> 5, tc = t & 31;
    if (slot < R_REL) {
        if (t < N_BASES) scomp[t] = comp[slot * N_BASES + t];
        __syncthreads();
        #pragma unroll
        for (int i = 0; i < 4; ++i) {
            int kk = tr + 8 * i;
            float acc = 0.f;
            #pragma unroll
            for (int bs = 0; bs < N_BASES; ++bs)
                acc += scomp[bs] * bases[((size_t)bs * DIM + k0 + kk) * DIM + n0 + tc];
            tile[kk][tc] = acc;
        }
    } else {
        #pragma unroll
        for (int i = 0; i < 4; ++i) {
            int kk = tr + 8 * i;
            tile[kk][tc] = root[(size_t)(k0 + kk) * DIM + n0 + tc];
        }
    }
    __syncthreads();
    size_t obase = ((size_t)layer * NSLOT + slot) * DIM * DIM;
    #pragma unroll
    for (int i = 0; i < 4; ++i) {
        int rr = tr + 8 * i;
        Wt[obase + (size_t)(n0 + rr) * DIM + k0 + tc] = f2bf(tile[tc][rr]);
    }
}

// ---------------- MFMA edge GEMM (per-chunk, prefetched): W in LDS, 128 edges/block,
//   32 edges/wave; esrc issued first, x-fragments issued before the barrier.
__launch_bounds__(256)
__global__ void edge_mfma_kernel(const uint4* __restrict__ esrc, const int* __restrict__ off,
                                 const ushort* __restrict__ xb, const ushort* __restrict__ Wt,
                                 ushort* __restrict__ T) {
    __shared__ __align__(16) ushort Ws[DIM * DIM];   // 32 KB, 16B-slot XOR swizzled
    __shared__ int soff[R_REL + 2];
    int t = threadIdx.x;
    int e0 = blockIdx.x * EB;
    int wv = t >> 6;            // wave -> edges [wv*32, wv*32+32)
    int l  = t & 63;
    int lr = l & 15;            // edge col within subtile / W row within n-tile
    int lk = l >> 4;            // k sub-segment 0..3
    int er0 = e0 + wv * 32 + lr;     // subtile 0 edge
    int er1 = er0 + 16;              // subtile 1 edge
    uint4 es0 = esrc[er0], es1 = esrc[er1];          // prefetch: no dependencies

    if (t < R_REL + 2) soff[t] = off[t];
    __syncthreads();
    if (e0 >= soff[R_REL + 1]) return;               // uniform exit (tail blocks)
    int r = 0;
    while (e0 >= soff[r + 1]) ++r;                   // block's W slot (0..40, uniform)

    // cooperative stage of W_r (32 KB) into LDS; 16B slot s of row -> s ^ (row&15)
    const ushort* Wr = Wt + (size_t)r * DIM * DIM;
    #pragma unroll
    for (int i = 0; i < 8; ++i) {
        int idx = t + 256 * i;                       // [0, 2048) 16B slots
        int row = idx >> 4, slot = idx & 15;
        uint4 v = *(const uint4*)(Wr + row * DIM + slot * 8);
        *(uint4*)(&Ws[row * DIM + ((slot ^ (row & 15)) * 8)]) = v;
    }

    // B-fragments (x^T): issue gathers before the barrier so they overlap it
    int s0 = (int)es0.x, q0 = (int)es0.y;
    int s1 = (int)es1.x, q1 = (int)es1.y;
    float esc0 = __uint_as_float(es0.z), esc1 = __uint_as_float(es1.z);
    const ushort* x0p = xb + (size_t)(s0 < 0 ? 0 : s0) * DIM;
    const ushort* x1p = xb + (size_t)(s1 < 0 ? 0 : s1) * DIM;
    short8 xf0[4], xf1[4];
    #pragma unroll
    for (int ks = 0; ks < 4; ++ks) {
        xf0[ks] = *(const short8*)(x0p + (ks * 4 + lk) * 8);
        xf1[ks] = *(const short8*)(x1p + (ks * 4 + lk) * 8);
    }
    __syncthreads();

    f32x4 acc0[8], acc1[8];
    #pragma unroll
    for (int mt = 0; mt < 8; ++mt) {
        acc0[mt] = (f32x4){0.f, 0.f, 0.f, 0.f};
        acc1[mt] = (f32x4){0.f, 0.f, 0.f, 0.f};
    }

    #pragma unroll
    for (int ks = 0; ks < 4; ++ks) {
        #pragma unroll
        for (int mt = 0; mt < 8; ++mt) {
            int row = mt * 16 + lr;
            int slot = (ks * 4 + lk) ^ lr;           // row&15 == lr
            short8 wf = *(const short8*)(&Ws[row * DIM + slot * 8]);
            acc0[mt] = __builtin_amdgcn_mfma_f32_16x16x32_bf16(wf, xf0[ks], acc0[mt], 0, 0, 0);
            acc1[mt] = __builtin_amdgcn_mfma_f32_16x16x32_bf16(wf, xf1[ks], acc1[mt], 0, 0, 0);
        }
    }

    // lane holds D[n = mt*16 + lk*4 + i][edge]; write to dst-CSR row q (skip padding q<0)
    ushort* T0 = T + (size_t)q0 * DIM;
    ushort* T1 = T + (size_t)q1 * DIM;
    #pragma unroll
    for (int mt = 0; mt < 8; ++mt) {
        if (q0 >= 0) {
            uint2 p0;
            p0.x = pk2bf(acc0[mt][0] * esc0, acc0[mt][1] * esc0);
            p0.y = pk2bf(acc0[mt][2] * esc0, acc0[mt][3] * esc0);
            *(uint2*)(T0 + mt * 16 + lk * 4) = p0;
        }
        if (q1 >= 0) {
            uint2 p1;
            p1.x = pk2bf(acc1[mt][0] * esc1, acc1[mt][1] * esc1);
            p1.y = pk2bf(acc1[mt][2] * esc1, acc1[mt][3] * esc1);
            *(uint2*)(T1 + mt * 16 + lk * 4) = p1;
        }
    }
}

// ---------------- aggregate: y[n,:] = bias + sum_{q in [ptr[n],ptr[n+1])} T[q,:] (sequential);
//   2 nodes per 128-thread block.
template<int OUT_BF16>
__global__ void aggregate_kernel(const int* __restrict__ ptr, const ushort* __restrict__ T,
                                 const float* __restrict__ bias, void* __restrict__ yout) {
    int t = threadIdx.x;
    int n = blockIdx.x * 2 + (t >> 6);   // N_NODES is even
    int tt = t & 63;                     // 64 threads per node, 2 cols each
    int s0 = ptr[n], s1 = ptr[n + 1];
    float a0 = bias[2 * tt], a1 = bias[2 * tt + 1];
    for (int q = s0; q < s1; ++q) {
        uint v = *(const uint*)(T + (size_t)q * DIM + 2 * tt);
        a0 += __uint_as_float(v << 16);
        a1 += __uint_as_float(v & 0xFFFF0000u);
    }
    if (OUT_BF16) {
        ((uint*)yout)[n * 64 + tt] = pk2bf(a0, a1);
    } else {
        ((float2*)yout)[n * 64 + tt] = make_float2(a0, a1);
    }
}

extern "C" void kernel_launch(void* const* d_in, const int* in_sizes, int n_in,
                              void* d_out, int out_size, void* d_ws, size_t ws_size,
                              hipStream_t stream) {
    const int*   node_index = (const int*)d_in[0];
    const int*   edge_index = (const int*)d_in[1];
    const int*   edge_type  = (const int*)d_in[2];
    // d_in[3] node_frequency: unused
    const float* node_emb   = (const float*)d_in[4];
    const float* comp0  = (const float*)d_in[5];
    const float* bases0 = (const float*)d_in[6];
    const float* root0  = (const float*)d_in[7];
    const float* bias0  = (const float*)d_in[8];
    const float* comp1  = (const float*)d_in[9];
    const float* bases1 = (const float*)d_in[10];
    const float* root1  = (const float*)d_in[11];
    const float* bias1  = (const float*)d_in[12];
    float* out = (float*)d_out;

    // ---- workspace layout (~109 MB) ----
    char* ws = (char*)d_ws;
    int*    c_cnt  = (int*)   (ws);                 //  3,200,000
    ushort* Wt     = (ushort*)(ws +  3200000);      //  2,686,976 (2 layers x 41 slots bf16 [n][k])
    ushort* x0b    = (ushort*)(ws +  5886976);      //  5,120,000
    ushort* y0b    = (ushort*)(ws + 11006976);      //  5,120,000
    uint4*  esrc   = (uint4*) (ws + 16126976);      //  5,523,456 (P2_MAX * 16B)
    int*    meta   = (int*)   (ws + 21650432);      //  1,024: off[42]@0 h[40]@64 cur[40]@128
    int*    cur2   = (int*)   (ws + 21651456);      //  80,000 (contiguous after meta)
    int*    deg    = (int*)   (ws + 21731456);      //  80,000 (contiguous after cur2)
    int*    ptr    = (int*)   (ws + 21811456);      //  80,256 (20001 ints)
    ushort* T      = (ushort*)(ws + 21891712);      // 87,040,000 (NE2 * 128 bf16)
    int* off = meta;
    int* h   = meta + 64;
    int* cur = meta + 128;

    // ---- build graph structures (shared by both layers) ----
    init_kernel<<<(N_NODES * R_REL + 255) / 256, 256, 0, stream>>>(c_cnt, meta, esrc);
    count_kernel<<<(N_EDGES + 255) / 256, 256, 0, stream>>>(edge_index, edge_type, c_cnt, h, deg);
    scans_kernel<<<1, 1024, 0, stream>>>(deg, h, ptr, off);
    place_kernel<<<(N_EDGES + N_NODES + 255) / 256, 256, 0, stream>>>(
        edge_index, edge_type, off, cur, c_cnt, ptr, cur2, esrc);
    gather_bf16_kernel<<<N_NODES * 16 / 256, 256, 0, stream>>>(node_emb, node_index, x0b);
    wtrans_kernel<<<2 * NSLOT * 16, 256, 0, stream>>>(comp0, bases0, root0,
                                                      comp1, bases1, root1, Wt);

    const int eBlocks = P2_MAX / EB;                      // 2697 uniform chunk blocks

    // ---- layer 0 ----
    edge_mfma_kernel<<<eBlocks, 256, 0, stream>>>(esrc, off, x0b, Wt, T);
    aggregate_kernel<1><<<N_NODES / 2, 128, 0, stream>>>(ptr, T, bias0, y0b);

    // ---- layer 1 ----
    edge_mfma_kernel<<<eBlocks, 256, 0, stream>>>(esrc, off, y0b,
                                                  Wt + (size_t)NSLOT * DIM * DIM, T);
    aggregate_kernel<0><<<N_NODES / 2, 128, 0, stream>>>(ptr, T, bias1, out);
}

// Round 11
// 256.421 us; speedup vs baseline: 13.2463x; 1.0686x over previous
//
#include <hip/hip_runtime.h>

#define N_NODES  20000
#define N_EDGES  320000
#define R_REL    40
#define N_BASES  34
#define DIM      128
#define EB       128                         // edges per block (edge GEMM tile M)
#define P_PAD    (N_EDGES + R_REL * EB)      // 325120: worst-case padded relation edges
#define ROOT_PAD ((N_NODES + EB - 1) / EB * EB)  // 20096
#define P2_MAX   (P_PAD + ROOT_PAD)          // 345216 (root edges = slot 40)
#define NE2      (N_EDGES + N_NODES)         // dst-CSR entries incl. root edges
#define NSLOT    (R_REL + 1)                 // 41 weight slots

#define INIT_B   ((N_NODES * R_REL + 255) / 256)   // 3125
#define GATH_B   (N_NODES * 16 / 256)              // 1250
#define WT_B     (2 * NSLOT * 16)                  // 1312

typedef unsigned int uint;
typedef unsigned short ushort;
typedef __attribute__((ext_vector_type(8))) short short8;   // 8 bf16 = 4 VGPRs
typedef __attribute__((ext_vector_type(4))) float f32x4;

__device__ __forceinline__ ushort f2bf(float f) {   // RNE fp32 -> bf16
    uint u = __float_as_uint(f);
    return (ushort)((u + 0x7FFFu + ((u >> 16) & 1u)) >> 16);
}
__device__ __forceinline__ uint pk2bf(float a, float b) {
    return (uint)f2bf(a) | ((uint)f2bf(b) << 16);
}

// ---------------- prep: init (zero/sentinel) + gather-bf16 + wtrans, one dispatch ----------------
__global__ void prep_kernel(int* __restrict__ c_cnt, int* __restrict__ meta_cur2_deg,
                            uint4* __restrict__ esrc,
                            const float* __restrict__ emb, const int* __restrict__ idx,
                            ushort* __restrict__ xb,
                            const float* __restrict__ comp0, const float* __restrict__ bases0,
                            const float* __restrict__ root0,
                            const float* __restrict__ comp1, const float* __restrict__ bases1,
                            const float* __restrict__ root1,
                            ushort* __restrict__ Wt) {
    int b = blockIdx.x;
    int t = threadIdx.x;
    if (b < INIT_B) {
        // ---- init ----
        int i = b * 256 + t;
        if (i < N_NODES * R_REL) c_cnt[i] = 0;
        if (i < P2_MAX) esrc[i] = make_uint4((uint)-1, (uint)-1, 0u, 0u);
        if (i < 256 + 2 * N_NODES) meta_cur2_deg[i] = 0;   // meta[256]+cur2[20000]+deg[20000]
    } else if (b < INIT_B + GATH_B) {
        // ---- gather + bf16 convert ----
        int g = (b - INIT_B) * 256 + t;
        int n = g >> 4, v = g & 15;
        const float4* s = (const float4*)(emb + (size_t)idx[n] * DIM + v * 8);
        float4 a = s[0], bb = s[1];
        uint4 o;
        o.x = pk2bf(a.x, a.y);  o.y = pk2bf(a.z, a.w);
        o.z = pk2bf(bb.x, bb.y); o.w = pk2bf(bb.z, bb.w);
        *(uint4*)(xb + (size_t)n * DIM + v * 8) = o;
    } else {
        // ---- wtrans: basis-combine + transpose + bf16, both layers ----
        __shared__ float tile[32][33];
        __shared__ float scomp[N_BASES];
        int wb = b - INIT_B - GATH_B;               // 0..1311
        int layer = (wb >= NSLOT * 16) ? 1 : 0;
        int bb2 = wb - layer * NSLOT * 16;
        const float* comp  = layer ? comp1  : comp0;
        const float* bases = layer ? bases1 : bases0;
        const float* root  = layer ? root1  : root0;
        int slot = bb2 >> 4;                        // 0..40
        int tb   = bb2 & 15;
        int k0 = (tb >> 2) * 32, n0 = (tb & 3) * 32;
        int tr = t >> 5, tc = t & 31;
        if (slot < R_REL) {
            if (t < N_BASES) scomp[t] = comp[slot * N_BASES + t];
            __syncthreads();
            #pragma unroll
            for (int i = 0; i < 4; ++i) {
                int kk = tr + 8 * i;
                float acc = 0.f;
                #pragma unroll
                for (int bs = 0; bs < N_BASES; ++bs)
                    acc += scomp[bs] * bases[((size_t)bs * DIM + k0 + kk) * DIM + n0 + tc];
                tile[kk][tc] = acc;
            }
        } else {
            #pragma unroll
            for (int i = 0; i < 4; ++i) {
                int kk = tr + 8 * i;
                tile[kk][tc] = root[(size_t)(k0 + kk) * DIM + n0 + tc];
            }
        }
        __syncthreads();
        size_t obase = ((size_t)layer * NSLOT + slot) * DIM * DIM;
        #pragma unroll
        for (int i = 0; i < 4; ++i) {
            int rr = tr + 8 * i;
            Wt[obase + (size_t)(n0 + rr) * DIM + k0 + tc] = f2bf(tile[tc][rr]);
        }
    }
}

// ---------------- counts c[dst*R+et], relation hist h, dst degree ----------------
__global__ void count_kernel(const int* __restrict__ ei, const int* __restrict__ et,
                             int* __restrict__ c, int* __restrict__ h,
                             int* __restrict__ deg) {
    __shared__ int hloc[R_REL];
    int t = threadIdx.x;
    if (t < R_REL) hloc[t] = 0;
    __syncthreads();
    int e = blockIdx.x * blockDim.x + t;
    if (e < N_EDGES) {
        int dst = ei[N_EDGES + e];
        int r   = et[e];
        atomicAdd(&c[dst * R_REL + r], 1);
        atomicAdd(&deg[dst], 1);
        atomicAdd(&hloc[r], 1);
    }
    __syncthreads();
    if (t < R_REL && hloc[t]) atomicAdd(&h[t], hloc[t]);
}

// ---------------- both scans in one 1024-thread block: dst-CSR ptr (deg+1), relation off ----
__global__ void scans_kernel(const int* __restrict__ deg, const int* __restrict__ h,
                             int* __restrict__ ptr, int* __restrict__ off) {
    __shared__ int part[1024];
    const int CHn = (N_NODES + 1023) / 1024;   // 20
    int t = threadIdx.x;
    int s = 0;
    for (int i = 0; i < CHn; ++i) {
        int idx = t * CHn + i;
        if (idx < N_NODES) s += deg[idx] + 1;  // +1 = root slot
    }
    part[t] = s;
    __syncthreads();
    for (int d = 1; d < 1024; d <<= 1) {
        int v = (t >= d) ? part[t - d] : 0;
        __syncthreads();
        part[t] += v;
        __syncthreads();
    }
    int base = (t > 0) ? part[t - 1] : 0;
    for (int i = 0; i < CHn; ++i) {
        int idx = t * CHn + i;
        if (idx < N_NODES) { ptr[idx] = base; base += deg[idx] + 1; }
    }
    if (t == 0) {
        ptr[N_NODES] = NE2;
        int acc = 0;
        off[0] = 0;
        for (int r = 0; r < R_REL; ++r) {
            acc += ((h[r] + EB - 1) / EB) * EB;
            off[r + 1] = acc;
        }
        off[R_REL + 1] = acc + ROOT_PAD;
    }
}

// ---------------- placement (finv computed inline from c_cnt): real + root edges ----------
//   esrc[p] = {src, qpos (dst-CSR position), bits(escale), 0}
__global__ void place_kernel(const int* __restrict__ ei, const int* __restrict__ et,
                             const int* __restrict__ off, int* __restrict__ cur,
                             const int* __restrict__ c_cnt,
                             const int* __restrict__ ptr, int* __restrict__ cur2,
                             uint4* __restrict__ esrc) {
    __shared__ int hloc[R_REL];
    __shared__ int base[R_REL];
    int t = threadIdx.x;
    if (t < R_REL) hloc[t] = 0;
    __syncthreads();
    int e = blockIdx.x * blockDim.x + t;       // covers N_EDGES + N_NODES
    int r = 0, myrank = 0, src = 0, dst = 0;
    bool isEdge = (e < N_EDGES);
    if (isEdge) {
        r = et[e]; src = ei[e]; dst = ei[N_EDGES + e];
        myrank = atomicAdd(&hloc[r], 1);
    }
    __syncthreads();
    if (t < R_REL) base[t] = hloc[t] ? atomicAdd(&cur[t], hloc[t]) : 0;
    __syncthreads();
    if (isEdge) {
        int p = off[r] + base[r] + myrank;
        int q = ptr[dst] + 1 + atomicAdd(&cur2[dst], 1);
        int cnt = c_cnt[dst * R_REL + r];
        float esc = 1.0f / (float)(cnt < 1 ? 1 : cnt);
        esrc[p] = make_uint4((uint)src, (uint)q, __float_as_uint(esc), 0u);
    } else if (e < N_EDGES + N_NODES) {
        int n = e - N_EDGES;
        esrc[off[R_REL] + n] = make_uint4((uint)n, (uint)ptr[n], 0x3f800000u, 0u);
    }
}

// ---------------- MFMA edge GEMM: 512 threads, 8 waves x 16 edges, W in LDS ----------------
__launch_bounds__(512)
__global__ void edge_mfma_kernel(const uint4* __restrict__ esrc, const int* __restrict__ off,
                                 const ushort* __restrict__ xb, const ushort* __restrict__ Wt,
                                 ushort* __restrict__ T) {
    __shared__ __align__(16) ushort Ws[DIM * DIM];   // 32 KB, 16B-slot XOR swizzled
    __shared__ int soff[R_REL + 2];
    int t = threadIdx.x;
    int e0 = blockIdx.x * EB;
    int wv = t >> 6;            // wave 0..7 -> edges [wv*16, wv*16+16)
    int l  = t & 63;
    int lr = l & 15;            // edge col within subtile / W row within n-tile
    int lk = l >> 4;            // k sub-segment 0..3
    int er = e0 + wv * 16 + lr;
    uint4 es = esrc[er];                             // prefetch: no dependencies

    if (t < R_REL + 2) soff[t] = off[t];
    __syncthreads();
    if (e0 >= soff[R_REL + 1]) return;               // uniform exit (tail blocks)
    int r = 0;
    while (e0 >= soff[r + 1]) ++r;                   // block's W slot (0..40, uniform)

    // cooperative stage of W_r (32 KB) into LDS; 16B slot s of row -> s ^ (row&15)
    const ushort* Wr = Wt + (size_t)r * DIM * DIM;
    #pragma unroll
    for (int i = 0; i < 4; ++i) {
        int idx = t + 512 * i;                       // [0, 2048) 16B slots
        int row = idx >> 4, slot = idx & 15;
        uint4 v = *(const uint4*)(Wr + row * DIM + slot * 8);
        *(uint4*)(&Ws[row * DIM + ((slot ^ (row & 15)) * 8)]) = v;
    }

    // B-fragments (x^T): issue gathers before the barrier so they overlap it
    int s0 = (int)es.x, q0 = (int)es.y;
    float esc = __uint_as_float(es.z);
    const ushort* xp = xb + (size_t)(s0 < 0 ? 0 : s0) * DIM;
    short8 xf[4];
    #pragma unroll
    for (int ks = 0; ks < 4; ++ks)
        xf[ks] = *(const short8*)(xp + (ks * 4 + lk) * 8);
    __syncthreads();

    f32x4 acc[8];
    #pragma unroll
    for (int mt = 0; mt < 8; ++mt) acc[mt] = (f32x4){0.f, 0.f, 0.f, 0.f};

    #pragma unroll
    for (int ks = 0; ks < 4; ++ks) {
        #pragma unroll
        for (int mt = 0; mt < 8; ++mt) {
            int row = mt * 16 + lr;
            int slot = (ks * 4 + lk) ^ lr;           // row&15 == lr
            short8 wf = *(const short8*)(&Ws[row * DIM + slot * 8]);
            acc[mt] = __builtin_amdgcn_mfma_f32_16x16x32_bf16(wf, xf[ks], acc[mt], 0, 0, 0);
        }
    }

    // lane holds D[n = mt*16 + lk*4 + i][edge]; write to dst-CSR row q (skip padding q<0)
    if (q0 >= 0) {
        ushort* T0 = T + (size_t)q0 * DIM;
        #pragma unroll
        for (int mt = 0; mt < 8; ++mt) {
            uint2 p0;
            p0.x = pk2bf(acc[mt][0] * esc, acc[mt][1] * esc);
            p0.y = pk2bf(acc[mt][2] * esc, acc[mt][3] * esc);
            *(uint2*)(T0 + mt * 16 + lk * 4) = p0;
        }
    }
}

// ---------------- aggregate: y[n,:] = bias + sum_{q in [ptr[n],ptr[n+1])} T[q,:] (sequential);
//   2 nodes per 128-thread block.
template<int OUT_BF16>
__global__ void aggregate_kernel(const int* __restrict__ ptr, const ushort* __restrict__ T,
                                 const float* __restrict__ bias, void* __restrict__ yout) {
    int t = threadIdx.x;
    int n = blockIdx.x * 2 + (t >> 6);   // N_NODES is even
    int tt = t & 63;                     // 64 threads per node, 2 cols each
    int s0 = ptr[n], s1 = ptr[n + 1];
    float a0 = bias[2 * tt], a1 = bias[2 * tt + 1];
    for (int q = s0; q < s1; ++q) {
        uint v = *(const uint*)(T + (size_t)q * DIM + 2 * tt);
        a0 += __uint_as_float(v << 16);
        a1 += __uint_as_float(v & 0xFFFF0000u);
    }
    if (OUT_BF16) {
        ((uint*)yout)[n * 64 + tt] = pk2bf(a0, a1);
    } else {
        ((float2*)yout)[n * 64 + tt] = make_float2(a0, a1);
    }
}

extern "C" void kernel_launch(void* const* d_in, const int* in_sizes, int n_in,
                              void* d_out, int out_size, void* d_ws, size_t ws_size,
                              hipStream_t stream) {
    const int*   node_index = (const int*)d_in[0];
    const int*   edge_index = (const int*)d_in[1];
    const int*   edge_type  = (const int*)d_in[2];
    // d_in[3] node_frequency: unused
    const float* node_emb   = (const float*)d_in[4];
    const float* comp0  = (const float*)d_in[5];
    const float* bases0 = (const float*)d_in[6];
    const float* root0  = (const float*)d_in[7];
    const float* bias0  = (const float*)d_in[8];
    const float* comp1  = (const float*)d_in[9];
    const float* bases1 = (const float*)d_in[10];
    const float* root1  = (const float*)d_in[11];
    const float* bias1  = (const float*)d_in[12];
    float* out = (float*)d_out;

    // ---- workspace layout (~109 MB) ----
    char* ws = (char*)d_ws;
    int*    c_cnt  = (int*)   (ws);                 //  3,200,000
    ushort* Wt     = (ushort*)(ws +  3200000);      //  2,686,976 (2 layers x 41 slots bf16 [n][k])
    ushort* x0b    = (ushort*)(ws +  5886976);      //  5,120,000
    ushort* y0b    = (ushort*)(ws + 11006976);      //  5,120,000
    uint4*  esrc   = (uint4*) (ws + 16126976);      //  5,523,456 (P2_MAX * 16B)
    int*    meta   = (int*)   (ws + 21650432);      //  1,024: off[42]@0 h[40]@64 cur[40]@128
    int*    cur2   = (int*)   (ws + 21651456);      //  80,000 (contiguous after meta)
    int*    deg    = (int*)   (ws + 21731456);      //  80,000 (contiguous after cur2)
    int*    ptr    = (int*)   (ws + 21811456);      //  80,256 (20001 ints)
    ushort* T      = (ushort*)(ws + 21891712);      // 87,040,000 (NE2 * 128 bf16)
    int* off = meta;
    int* h   = meta + 64;
    int* cur = meta + 128;

    // ---- build graph structures (shared by both layers) ----
    prep_kernel<<<INIT_B + GATH_B + WT_B, 256, 0, stream>>>(
        c_cnt, meta, esrc, node_emb, node_index, x0b,
        comp0, bases0, root0, comp1, bases1, root1, Wt);
    count_kernel<<<(N_EDGES + 255) / 256, 256, 0, stream>>>(edge_index, edge_type, c_cnt, h, deg);
    scans_kernel<<<1, 1024, 0, stream>>>(deg, h, ptr, off);
    place_kernel<<<(N_EDGES + N_NODES + 255) / 256, 256, 0, stream>>>(
        edge_index, edge_type, off, cur, c_cnt, ptr, cur2, esrc);

    const int eBlocks = P2_MAX / EB;                      // 2697 uniform chunk blocks

    // ---- layer 0 ----
    edge_mfma_kernel<<<eBlocks, 512, 0, stream>>>(esrc, off, x0b, Wt, T);
    aggregate_kernel<1><<<N_NODES / 2, 128, 0, stream>>>(ptr, T, bias0, y0b);

    // ---- layer 1 ----
    edge_mfma_kernel<<<eBlocks, 512, 0, stream>>>(esrc, off, y0b,
                                                  Wt + (size_t)NSLOT * DIM * DIM, T);
    aggregate_kernel<0><<<N_NODES / 2, 128, 0, stream>>>(ptr, T, bias1, out);
}